// Round 8
// baseline (1543.028 us; speedup 1.0000x reference)
//
#include <hip/hip_runtime.h>

#define NTOT 4096
#define NBATCH 4
#define KNN 20
#define JSPLIT 8
#define KSUB 16
#define KMRG 28

constexpr float NEG_INF = -3.0e38f;

__device__ __forceinline__ unsigned pk(float f, int j) {
  unsigned u = __float_as_uint(f);
  u = (u & 0x80000000u) ? ~u : (u | 0x80000000u);
  return (u & 0xFFFFF000u) | (unsigned)j;
}

__device__ __forceinline__ void pins16(unsigned u, unsigned (&tv)[KSUB]) {
  if (u > tv[0]) {
    tv[0] = u;
#pragma unroll
    for (int x = 1; x < KSUB; x++) {
      unsigned mn = min(tv[0], tv[x]);
      unsigned mx = max(tv[0], tv[x]);
      tv[0] = mn;
      tv[x] = mx;
    }
  }
}

__device__ __forceinline__ void topk_insert(float val, int j, float (&tv)[KNN],
                                            int (&tj)[KNN], float& minv, int& minp) {
  if (val > minv) {
#pragma unroll
    for (int u = 0; u < KNN; u++) {
      bool w = (minp == u);
      tv[u] = w ? val : tv[u];
      tj[u] = w ? j : tj[u];
    }
    minv = tv[0];
    minp = 0;
#pragma unroll
    for (int u = 1; u < KNN; u++)
      if (tv[u] < minv) { minv = tv[u]; minp = u; }
  }
}

// ---------------- prep: fold BN scale into weights ----------------
__global__ void prep_w(const float* __restrict__ W, const float* __restrict__ gg,
                       const float* __restrict__ bb, const float* __restrict__ mm,
                       const float* __restrict__ vv, float* __restrict__ Wc,
                       float* __restrict__ bias, int O, int C) {
  int t = blockIdx.x * 256 + threadIdx.x;
  if (t >= 2 * O * C) return;
  int o2 = t / C, c = t - o2 * C;
  int o = (o2 < O) ? o2 : o2 - O;
  float s = gg[o] * rsqrtf(vv[o] + 1e-5f);
  float w = (o2 < O) ? W[o * 2 * C + c] * s
                     : (W[o * 2 * C + C + c] - W[o * 2 * C + c]) * s;
  Wc[o2 * C + c] = w;
  if (o2 >= O && c == 0) bias[o] = bb[o] - mm[o] * s;
}

// ---------------- half squared norms ----------------
template <int C>
__global__ void sqh_k(const float* __restrict__ f, float* __restrict__ sqh) {
  int p = blockIdx.x * 256 + threadIdx.x;
  const float* r = f + (size_t)p * C;
  float s = 0.f;
#pragma unroll
  for (int c4 = 0; c4 < C / 4; c4++) {
    float4 v = *(const float4*)&r[c4 * 4];
    s += v.x * v.x + v.y * v.y + v.z * v.z + v.w * v.w;
  }
  sqh[p] = 0.5f * s;
}

// ---------------- KNN C=3 stage 1: packed top-16, 4 sub-lists/row ----------
__global__ __launch_bounds__(256) void knn3_g(const float* __restrict__ feat,
                                              unsigned* __restrict__ cval) {
  __shared__ __align__(16) float sA[64 * 4];

  int tid = threadIdx.x;
  int rb = blockIdx.x & 63;
  int b = blockIdx.x >> 6;
  int row0 = rb * 64;
  int r = tid >> 2, q = tid & 3;
  int i = row0 + r;
  const float* fb = feat + (size_t)b * NTOT * 3;

  float c0 = fb[(size_t)i * 3 + 0];
  float c1 = fb[(size_t)i * 3 + 1];
  float c2 = fb[(size_t)i * 3 + 2];

  unsigned tv[KSUB];
#pragma unroll
  for (int t = 0; t < KSUB; t++) tv[t] = 0u;

  for (int jt = 0; jt < NTOT; jt += 64) {
    __syncthreads();
    if (tid < 64) {
      sA[tid * 4 + 0] = fb[(size_t)(jt + tid) * 3 + 0];
      sA[tid * 4 + 1] = fb[(size_t)(jt + tid) * 3 + 1];
      sA[tid * 4 + 2] = fb[(size_t)(jt + tid) * 3 + 2];
    }
    __syncthreads();

#pragma unroll
    for (int cc = 0; cc < 16; cc++) {
      int jl = cc * 4 + q;
      float d0 = c0 - sA[jl * 4];
      float d1 = c1 - sA[jl * 4 + 1];
      float d2 = c2 - sA[jl * 4 + 2];
      float val = -(d0 * d0 + d1 * d1 + d2 * d2);
      pins16(pk(val, jt + jl), tv);
    }
  }

  int p = b * NTOT + row0 + r;
#pragma unroll
  for (int t = 0; t < KSUB; t++)
    cval[(size_t)(q * KSUB + t) * (NBATCH * NTOT) + p] = tv[t];
}

// ---------------- KNN stage 1 (C=64/128): dot-form + packed top-16 ----------
// 128x128 tile, 8x8/thread, BK=16 staging. LDS = 17.9+34.8+0.5 = 52 KB ->
// 3 blocks/CU. Dt bounce layout identical to the verified R6 version (128x68,
// float4, two 64-col phases). JSPLIT=8 -> 256 candidates per sel thread.
template <int C>
__global__ __launch_bounds__(256, 3) void knn_g(const float* __restrict__ feat,
                                                const float* __restrict__ sqh,
                                                unsigned* __restrict__ cval) {
  constexpr int P = 140;
  constexpr int BK = 16;
  __shared__ float As[BK * P];
  __shared__ float Bs[BK * P];
  __shared__ float Dt[128 * 68];
  __shared__ float sqB[128];

  int tid = threadIdx.x;
  int js = blockIdx.x & (JSPLIT - 1);
  int it = (blockIdx.x >> 3) & 31;
  int b = blockIdx.x >> 8;
  int i0 = it * 128;
  const float* fb = feat + (size_t)b * NTOT * C;

  int tx = tid & 15, ty = tid >> 4;
  int aoff = (ty * 8) + (((ty * 8) >> 5) << 2);
  int boff = (tx * 8) + (((tx * 8) >> 5) << 2);
  int selr = tid >> 1;
  int sels = tid & 1;

  unsigned tv[KSUB];
#pragma unroll
  for (int t = 0; t < KSUB; t++) tv[t] = 0u;

  for (int jt = 0; jt < NTOT / (128 * JSPLIT); jt++) {
    int j0 = js * (NTOT / JSPLIT) + jt * 128;
    if (tid < 128) sqB[tid] = sqh[b * NTOT + j0 + tid];

    float acc[8][8];
#pragma unroll
    for (int ii = 0; ii < 8; ii++)
#pragma unroll
      for (int jj = 0; jj < 8; jj++) acc[ii][jj] = 0.f;

    for (int kc = 0; kc < C; kc += BK) {
      __syncthreads();
#pragma unroll
      for (int l = 0; l < 2; l++) {
        int e = tid + 256 * l;       // 512 float4 = 128 rows x 4 f4-cols
        int rr = e >> 2, c4 = e & 3;
        int sc = rr + ((rr >> 5) << 2);
        float4 va = *(const float4*)&fb[(size_t)(i0 + rr) * C + kc + c4 * 4];
        As[(c4 * 4 + 0) * P + sc] = va.x;
        As[(c4 * 4 + 1) * P + sc] = va.y;
        As[(c4 * 4 + 2) * P + sc] = va.z;
        As[(c4 * 4 + 3) * P + sc] = va.w;
        float4 vb = *(const float4*)&fb[(size_t)(j0 + rr) * C + kc + c4 * 4];
        Bs[(c4 * 4 + 0) * P + sc] = vb.x;
        Bs[(c4 * 4 + 1) * P + sc] = vb.y;
        Bs[(c4 * 4 + 2) * P + sc] = vb.z;
        Bs[(c4 * 4 + 3) * P + sc] = vb.w;
      }
      __syncthreads();
#pragma unroll 8
      for (int k = 0; k < BK; k++) {
        float4 a0 = *(const float4*)&As[k * P + aoff];
        float4 a1 = *(const float4*)&As[k * P + aoff + 4];
        float4 b0 = *(const float4*)&Bs[k * P + boff];
        float4 b1 = *(const float4*)&Bs[k * P + boff + 4];
        float av[8] = {a0.x, a0.y, a0.z, a0.w, a1.x, a1.y, a1.z, a1.w};
        float bv[8] = {b0.x, b0.y, b0.z, b0.w, b1.x, b1.y, b1.z, b1.w};
#pragma unroll
        for (int ii = 0; ii < 8; ii++)
#pragma unroll
          for (int jj = 0; jj < 8; jj++)
            acc[ii][jj] = fmaf(av[ii], bv[jj], acc[ii][jj]);
      }
    }

    // phase A: j-tile cols 0..63 (threads tx<8) — verified R6 layout
    if (tx < 8) {
      float4 q0 = *(const float4*)&sqB[tx * 8];
      float4 q1 = *(const float4*)&sqB[tx * 8 + 4];
#pragma unroll
      for (int ii = 0; ii < 8; ii++) {
        float4 o0 = make_float4(acc[ii][0] - q0.x, acc[ii][1] - q0.y,
                                acc[ii][2] - q0.z, acc[ii][3] - q0.w);
        float4 o1 = make_float4(acc[ii][4] - q1.x, acc[ii][5] - q1.y,
                                acc[ii][6] - q1.z, acc[ii][7] - q1.w);
        *(float4*)&Dt[(ty * 8 + ii) * 68 + tx * 8] = o0;
        *(float4*)&Dt[(ty * 8 + ii) * 68 + tx * 8 + 4] = o1;
      }
    }
    __syncthreads();
#pragma unroll
    for (int t4 = 0; t4 < 8; t4++) {
      float4 v = *(const float4*)&Dt[selr * 68 + sels * 32 + t4 * 4];
      int jb = j0 + sels * 32 + t4 * 4;
      pins16(pk(v.x, jb + 0), tv);
      pins16(pk(v.y, jb + 1), tv);
      pins16(pk(v.z, jb + 2), tv);
      pins16(pk(v.w, jb + 3), tv);
    }
    __syncthreads();
    // phase B: j-tile cols 64..127 (threads tx>=8)
    if (tx >= 8) {
      float4 q0 = *(const float4*)&sqB[tx * 8];
      float4 q1 = *(const float4*)&sqB[tx * 8 + 4];
#pragma unroll
      for (int ii = 0; ii < 8; ii++) {
        float4 o0 = make_float4(acc[ii][0] - q0.x, acc[ii][1] - q0.y,
                                acc[ii][2] - q0.z, acc[ii][3] - q0.w);
        float4 o1 = make_float4(acc[ii][4] - q1.x, acc[ii][5] - q1.y,
                                acc[ii][6] - q1.z, acc[ii][7] - q1.w);
        *(float4*)&Dt[(ty * 8 + ii) * 68 + (tx - 8) * 8] = o0;
        *(float4*)&Dt[(ty * 8 + ii) * 68 + (tx - 8) * 8 + 4] = o1;
      }
    }
    __syncthreads();
#pragma unroll
    for (int t4 = 0; t4 < 8; t4++) {
      float4 v = *(const float4*)&Dt[selr * 68 + sels * 32 + t4 * 4];
      int jb = j0 + 64 + sels * 32 + t4 * 4;
      pins16(pk(v.x, jb + 0), tv);
      pins16(pk(v.y, jb + 1), tv);
      pins16(pk(v.z, jb + 2), tv);
      pins16(pk(v.w, jb + 3), tv);
    }
    __syncthreads();
  }

  int p = b * NTOT + i0 + selr;
  int sub = js * 2 + sels;  // 0..15
#pragma unroll
  for (int t = 0; t < KSUB; t++)
    cval[(size_t)(sub * KSUB + t) * (NBATCH * NTOT) + p] = tv[t];
}

// ---------------- merge + exact refine ----------------
template <int C, int NSUB>
__global__ __launch_bounds__(128) void kref_k(const float* __restrict__ feat,
                                              const unsigned* __restrict__ cval,
                                              int* __restrict__ outidx) {
  int p = blockIdx.x * 128 + threadIdx.x;
  int b = p >> 12;
  unsigned tv[KMRG];
#pragma unroll
  for (int t = 0; t < KMRG; t++) tv[t] = 0u;
#pragma unroll 2
  for (int t = 0; t < NSUB * KSUB; t++) {
    unsigned u = cval[(size_t)t * (NBATCH * NTOT) + p];
    if (u > tv[0]) {
      tv[0] = u;
#pragma unroll
      for (int x = 1; x < KMRG; x++) {
        unsigned mn = min(tv[0], tv[x]);
        unsigned mx = max(tv[0], tv[x]);
        tv[0] = mn;
        tv[x] = mx;
      }
    }
  }

  const float* fb = feat + (size_t)b * NTOT * C;
  const float* fi = fb + (size_t)(p & (NTOT - 1)) * C;
  float ev[KNN];
  int ej[KNN];
#pragma unroll
  for (int t = 0; t < KNN; t++) { ev[t] = NEG_INF; ej[t] = 0; }
  float minv = NEG_INF;
  int minp = 0;
#pragma unroll 1
  for (int u = 0; u < KMRG; u++) {
    int j = (int)(tv[u] & 0xFFFu);
    const float* fj = fb + (size_t)j * C;
    float val;
    if (C == 3) {
      float d0 = fi[0] - fj[0];
      float d1 = fi[1] - fj[1];
      float d2 = fi[2] - fj[2];
      val = -(d0 * d0 + d1 * d1 + d2 * d2);
    } else {
      float a0 = 0.f, a1 = 0.f, a2 = 0.f, a3 = 0.f;
#pragma unroll 4
      for (int c4 = 0; c4 < C / 4; c4++) {
        float4 x = *(const float4*)&fi[c4 * 4];
        float4 y = *(const float4*)&fj[c4 * 4];
        float d0 = x.x - y.x, d1 = x.y - y.y, d2 = x.z - y.z, d3 = x.w - y.w;
        a0 = fmaf(d0, d0, a0);
        a1 = fmaf(d1, d1, a1);
        a2 = fmaf(d2, d2, a2);
        a3 = fmaf(d3, d3, a3);
      }
      val = -((a0 + a1) + (a2 + a3));
    }
    topk_insert(val, j, ev, ej, minv, minp);
  }
#pragma unroll
  for (int t = 0; t < KNN; t++) outidx[(size_t)p * KNN + t] = ej[t];
}

// ---------------- 128x128 GEMM (K>=16): Y = A * Wc^T (+bias on V half) ------
__global__ __launch_bounds__(256) void gemm128(const float* __restrict__ A,
                                               const float* __restrict__ Wc,
                                               const float* __restrict__ bias,
                                               float* __restrict__ Y, int K, int N2,
                                               int O) {
  constexpr int P = 140;
  __shared__ float As[16 * P];
  __shared__ float Bs[16 * P];
  int tid = threadIdx.x;
  int n0 = blockIdx.x * 128;
  int m0 = blockIdx.y * 128;
  int tx = tid & 15, ty = tid >> 4;
  int aoff = (ty * 8) + (((ty * 8) >> 5) << 2);
  int boff = (tx * 8) + (((tx * 8) >> 5) << 2);
  float acc[8][8];
#pragma unroll
  for (int ii = 0; ii < 8; ii++)
#pragma unroll
    for (int jj = 0; jj < 8; jj++) acc[ii][jj] = 0.f;

  for (int kc = 0; kc < K; kc += 16) {
    __syncthreads();
#pragma unroll
    for (int l = 0; l < 2; l++) {
      int e = tid + 256 * l;
      int rr = e >> 2, c4 = e & 3;
      int sc = rr + ((rr >> 5) << 2);
      float4 va = *(const float4*)&A[(size_t)(m0 + rr) * K + kc + c4 * 4];
      As[(c4 * 4 + 0) * P + sc] = va.x;
      As[(c4 * 4 + 1) * P + sc] = va.y;
      As[(c4 * 4 + 2) * P + sc] = va.z;
      As[(c4 * 4 + 3) * P + sc] = va.w;
      float4 vb = *(const float4*)&Wc[(size_t)(n0 + rr) * K + kc + c4 * 4];
      Bs[(c4 * 4 + 0) * P + sc] = vb.x;
      Bs[(c4 * 4 + 1) * P + sc] = vb.y;
      Bs[(c4 * 4 + 2) * P + sc] = vb.z;
      Bs[(c4 * 4 + 3) * P + sc] = vb.w;
    }
    __syncthreads();
#pragma unroll 8
    for (int k = 0; k < 16; k++) {
      float4 a0 = *(const float4*)&As[k * P + aoff];
      float4 a1 = *(const float4*)&As[k * P + aoff + 4];
      float4 b0 = *(const float4*)&Bs[k * P + boff];
      float4 b1 = *(const float4*)&Bs[k * P + boff + 4];
      float av[8] = {a0.x, a0.y, a0.z, a0.w, a1.x, a1.y, a1.z, a1.w};
      float bv[8] = {b0.x, b0.y, b0.z, b0.w, b1.x, b1.y, b1.z, b1.w};
#pragma unroll
      for (int ii = 0; ii < 8; ii++)
#pragma unroll
        for (int jj = 0; jj < 8; jj++)
          acc[ii][jj] = fmaf(av[ii], bv[jj], acc[ii][jj]);
    }
  }

  int col0 = n0 + tx * 8;
  float bv[8];
#pragma unroll
  for (int jj = 0; jj < 8; jj++) {
    int col = col0 + jj;
    bv[jj] = (col >= O) ? bias[col - O] : 0.f;
  }
#pragma unroll
  for (int ii = 0; ii < 8; ii++) {
    int row = m0 + ty * 8 + ii;
    float4 o0, o1;
    o0.x = acc[ii][0] + bv[0];
    o0.y = acc[ii][1] + bv[1];
    o0.z = acc[ii][2] + bv[2];
    o0.w = acc[ii][3] + bv[3];
    o1.x = acc[ii][4] + bv[4];
    o1.y = acc[ii][5] + bv[5];
    o1.z = acc[ii][6] + bv[6];
    o1.w = acc[ii][7] + bv[7];
    *(float4*)&Y[(size_t)row * N2 + col0] = o0;
    *(float4*)&Y[(size_t)row * N2 + col0 + 4] = o1;
  }
}

// ---------------- small GEMM for layer 1 (K=3) ----------------
__global__ __launch_bounds__(256) void gemm_k(const float* __restrict__ A,
                                              const float* __restrict__ Wc,
                                              const float* __restrict__ bias,
                                              float* __restrict__ Y, int K, int N2,
                                              int O) {
  __shared__ float As[8 * 68];
  __shared__ float Bs[8 * 68];
  int tid = threadIdx.x;
  int n0 = blockIdx.x * 64;
  int m0 = blockIdx.y * 64;
  int tx = tid & 15, ty = tid >> 4;
  float acc[4][4] = {};
  for (int k0 = 0; k0 < K; k0 += 8) {
    __syncthreads();
    {
      int e = tid, mm = e >> 3, kk = e & 7;
      As[kk * 68 + mm] = (k0 + kk < K) ? A[(size_t)(m0 + mm) * K + k0 + kk] : 0.f;
      int nn = mm;
      Bs[kk * 68 + nn] = (k0 + kk < K) ? Wc[(size_t)(n0 + nn) * K + k0 + kk] : 0.f;
      e = tid + 256;
      mm = e >> 3;
      kk = e & 7;
      As[kk * 68 + mm] = (k0 + kk < K) ? A[(size_t)(m0 + mm) * K + k0 + kk] : 0.f;
      nn = mm;
      Bs[kk * 68 + nn] = (k0 + kk < K) ? Wc[(size_t)(n0 + nn) * K + k0 + kk] : 0.f;
    }
    __syncthreads();
#pragma unroll
    for (int kk = 0; kk < 8; kk++) {
      float4 av = *(float4*)&As[kk * 68 + ty * 4];
      float4 bv = *(float4*)&Bs[kk * 68 + tx * 4];
      float a[4] = {av.x, av.y, av.z, av.w};
      float bb2[4] = {bv.x, bv.y, bv.z, bv.w};
#pragma unroll
      for (int ii = 0; ii < 4; ii++)
#pragma unroll
        for (int jj = 0; jj < 4; jj++) acc[ii][jj] += a[ii] * bb2[jj];
    }
  }
  int col = n0 + tx * 4;
  bool isV = (col >= O);
  float b0 = 0.f, b1 = 0.f, b2 = 0.f, b3 = 0.f;
  if (isV) {
    b0 = bias[col + 0 - O];
    b1 = bias[col + 1 - O];
    b2 = bias[col + 2 - O];
    b3 = bias[col + 3 - O];
  }
#pragma unroll
  for (int ii = 0; ii < 4; ii++) {
    int row = m0 + ty * 4 + ii;
    float4 o4;
    o4.x = acc[ii][0] + b0;
    o4.y = acc[ii][1] + b1;
    o4.z = acc[ii][2] + b2;
    o4.w = acc[ii][3] + b3;
    *(float4*)&Y[(size_t)row * N2 + col] = o4;
  }
}

// ---------------- gather + max + LeakyReLU (float4) ----------------
template <int O>
__global__ __launch_bounds__(256) void gmax_v(const float* __restrict__ Y,
                                              const int* __restrict__ idx,
                                              float* __restrict__ out) {
  constexpr int T = O / 4;
  constexpr int G = 256 / T;
  int tid = threadIdx.x;
  int p = blockIdx.x * G + tid / T;
  int o4 = (tid % T) * 4;
  int b = p >> 12;
  constexpr int N2 = 2 * O;
  const int* ip = idx + (size_t)p * KNN;
  float4 m = make_float4(NEG_INF, NEG_INF, NEG_INF, NEG_INF);
#pragma unroll
  for (int k = 0; k < KNN; k++) {
    int j = ip[k];
    float4 v = *(const float4*)&Y[((size_t)(b * NTOT + j)) * N2 + o4];
    m.x = fmaxf(m.x, v.x);
    m.y = fmaxf(m.y, v.y);
    m.z = fmaxf(m.z, v.z);
    m.w = fmaxf(m.w, v.w);
  }
  float4 c = *(const float4*)&Y[(size_t)p * N2 + O + o4];
  float4 o;
  o.x = c.x + m.x;
  o.y = c.y + m.y;
  o.z = c.z + m.z;
  o.w = c.w + m.w;
  o.x = (o.x >= 0.f) ? o.x : 0.2f * o.x;
  o.y = (o.y >= 0.f) ? o.y : 0.2f * o.y;
  o.z = (o.z >= 0.f) ? o.z : 0.2f * o.z;
  o.w = (o.w >= 0.f) ? o.w : 0.2f * o.w;
  *(float4*)&out[(size_t)p * O + o4] = o;
}

// ---------------- host side ----------------
template <int C, int O>
static void run_layer(const float* fin, void* const* w5, float* fout, float* Wc,
                      float* biasb, int* idx, float* Y, float* sqh,
                      unsigned* cval, hipStream_t stream) {
  const float* W = (const float*)w5[0];
  const float* g = (const float*)w5[1];
  const float* bb = (const float*)w5[2];
  const float* mm = (const float*)w5[3];
  const float* vv = (const float*)w5[4];
  int N2 = 2 * O;
  prep_w<<<(2 * O * C + 255) / 256, 256, 0, stream>>>(W, g, bb, mm, vv, Wc, biasb, O, C);
  if (C == 3) {
    knn3_g<<<NBATCH * (NTOT / 64), 256, 0, stream>>>(fin, cval);
    kref_k<3, 4><<<NBATCH * NTOT / 128, 128, 0, stream>>>(fin, cval, idx);
    dim3 gg(N2 / 64, NBATCH * NTOT / 64);
    gemm_k<<<gg, 256, 0, stream>>>(fin, Wc, biasb, Y, C, N2, O);
  } else {
    constexpr int CC = (C == 3) ? 64 : C;
    sqh_k<CC><<<NBATCH * NTOT / 256, 256, 0, stream>>>(fin, sqh);
    knn_g<CC><<<NBATCH * 32 * JSPLIT, 256, 0, stream>>>(fin, sqh, cval);
    kref_k<CC, JSPLIT * 2><<<NBATCH * NTOT / 128, 128, 0, stream>>>(fin, cval, idx);
    dim3 gg(N2 / 128, NBATCH * NTOT / 128);
    gemm128<<<gg, 256, 0, stream>>>(fin, Wc, biasb, Y, C, N2, O);
  }
  gmax_v<O><<<NBATCH * NTOT / (256 / (O / 4)), 256, 0, stream>>>(Y, idx, fout);
}

extern "C" void kernel_launch(void* const* d_in, const int* in_sizes, int n_in,
                              void* d_out, int out_size, void* d_ws, size_t ws_size,
                              hipStream_t stream) {
  const float* x = (const float*)d_in[0];
  char* ws = (char*)d_ws;
  float* Wc = (float*)(ws + 0);            // 262144
  float* biasb = (float*)(ws + 262144);    // 1024
  int* idx = (int*)(ws + 263168);          // 1310720
  float* sqh = (float*)(ws + 1573888);     // 65536
  float* Y = (float*)(ws + 1639424);       // 33554432 -> ends 35193856
  float* x1 = (float*)(ws + 35193856);     // 4194304
  float* x2 = (float*)(ws + 39388160);     // 4194304
  float* x3 = (float*)(ws + 43582464);     // 8388608

  unsigned* cval = (unsigned*)Y;           // 16*16*16384*4 = 16.8 MB, pre-gemm

  float* outf = (float*)d_out;

  run_layer<3, 64>(x, d_in + 1, x1, Wc, biasb, idx, Y, sqh, cval, stream);
  run_layer<64, 64>(x1, d_in + 6, x2, Wc, biasb, idx, Y, sqh, cval, stream);
  run_layer<64, 128>(x2, d_in + 11, x3, Wc, biasb, idx, Y, sqh, cval, stream);
  run_layer<128, 256>(x3, d_in + 16, outf, Wc, biasb, idx, Y, sqh, cval, stream);
}

// Round 9
// 1392.102 us; speedup vs baseline: 1.1084x; 1.1084x over previous
//
#include <hip/hip_runtime.h>

#define NTOT 4096
#define NBATCH 4
#define KNN 20
#define JSPLIT 8
#define KSUB 16
#define KMRG 28

constexpr float NEG_INF = -3.0e38f;

__device__ __forceinline__ unsigned pk(float f, int j) {
  unsigned u = __float_as_uint(f);
  u = (u & 0x80000000u) ? ~u : (u | 0x80000000u);
  return (u & 0xFFFFF000u) | (unsigned)j;
}

__device__ __forceinline__ void pins16(unsigned u, unsigned (&tv)[KSUB]) {
  if (u > tv[0]) {
    tv[0] = u;
#pragma unroll
    for (int x = 1; x < KSUB; x++) {
      unsigned mn = min(tv[0], tv[x]);
      unsigned mx = max(tv[0], tv[x]);
      tv[0] = mn;
      tv[x] = mx;
    }
  }
}

// conservative quad gate: pk(max4,0xFFF) >= pk(v_i, j) for any v_i <= max4,
// so a skipped quad can never contain an inserting candidate.
__device__ __forceinline__ void pins16_quad(float4 v, int jb, unsigned (&tv)[KSUB]) {
  float m4 = fmaxf(fmaxf(v.x, v.y), fmaxf(v.z, v.w));
  if (pk(m4, 0xFFF) > tv[0]) {
    pins16(pk(v.x, jb + 0), tv);
    pins16(pk(v.y, jb + 1), tv);
    pins16(pk(v.z, jb + 2), tv);
    pins16(pk(v.w, jb + 3), tv);
  }
}

__device__ __forceinline__ void topk_insert(float val, int j, float (&tv)[KNN],
                                            int (&tj)[KNN], float& minv, int& minp) {
  if (val > minv) {
#pragma unroll
    for (int u = 0; u < KNN; u++) {
      bool w = (minp == u);
      tv[u] = w ? val : tv[u];
      tj[u] = w ? j : tj[u];
    }
    minv = tv[0];
    minp = 0;
#pragma unroll
    for (int u = 1; u < KNN; u++)
      if (tv[u] < minv) { minv = tv[u]; minp = u; }
  }
}

// ---------------- prep: fold BN scale into weights ----------------
__global__ void prep_w(const float* __restrict__ W, const float* __restrict__ gg,
                       const float* __restrict__ bb, const float* __restrict__ mm,
                       const float* __restrict__ vv, float* __restrict__ Wc,
                       float* __restrict__ bias, int O, int C) {
  int t = blockIdx.x * 256 + threadIdx.x;
  if (t >= 2 * O * C) return;
  int o2 = t / C, c = t - o2 * C;
  int o = (o2 < O) ? o2 : o2 - O;
  float s = gg[o] * rsqrtf(vv[o] + 1e-5f);
  float w = (o2 < O) ? W[o * 2 * C + c] * s
                     : (W[o * 2 * C + C + c] - W[o * 2 * C + c]) * s;
  Wc[o2 * C + c] = w;
  if (o2 >= O && c == 0) bias[o] = bb[o] - mm[o] * s;
}

// ---------------- half squared norms ----------------
template <int C>
__global__ void sqh_k(const float* __restrict__ f, float* __restrict__ sqh) {
  int p = blockIdx.x * 256 + threadIdx.x;
  const float* r = f + (size_t)p * C;
  float s = 0.f;
#pragma unroll
  for (int c4 = 0; c4 < C / 4; c4++) {
    float4 v = *(const float4*)&r[c4 * 4];
    s += v.x * v.x + v.y * v.y + v.z * v.z + v.w * v.w;
  }
  sqh[p] = 0.5f * s;
}

// ---------------- KNN C=3 stage 1: packed top-16, 4 sub-lists/row ----------
__global__ __launch_bounds__(256) void knn3_g(const float* __restrict__ feat,
                                              unsigned* __restrict__ cval) {
  __shared__ __align__(16) float sA[64 * 4];

  int tid = threadIdx.x;
  int rb = blockIdx.x & 63;
  int b = blockIdx.x >> 6;
  int row0 = rb * 64;
  int r = tid >> 2, q = tid & 3;
  int i = row0 + r;
  const float* fb = feat + (size_t)b * NTOT * 3;

  float c0 = fb[(size_t)i * 3 + 0];
  float c1 = fb[(size_t)i * 3 + 1];
  float c2 = fb[(size_t)i * 3 + 2];

  unsigned tv[KSUB];
#pragma unroll
  for (int t = 0; t < KSUB; t++) tv[t] = 0u;

  for (int jt = 0; jt < NTOT; jt += 64) {
    __syncthreads();
    if (tid < 64) {
      sA[tid * 4 + 0] = fb[(size_t)(jt + tid) * 3 + 0];
      sA[tid * 4 + 1] = fb[(size_t)(jt + tid) * 3 + 1];
      sA[tid * 4 + 2] = fb[(size_t)(jt + tid) * 3 + 2];
    }
    __syncthreads();

#pragma unroll
    for (int cc = 0; cc < 4; cc++) {
      float vq[4];
#pragma unroll
      for (int u = 0; u < 4; u++) {
        int jl = (cc * 4 + u) * 4 + q;
        float d0 = c0 - sA[jl * 4];
        float d1 = c1 - sA[jl * 4 + 1];
        float d2 = c2 - sA[jl * 4 + 2];
        vq[u] = -(d0 * d0 + d1 * d1 + d2 * d2);
      }
      float m4 = fmaxf(fmaxf(vq[0], vq[1]), fmaxf(vq[2], vq[3]));
      if (pk(m4, 0xFFF) > tv[0]) {
#pragma unroll
        for (int u = 0; u < 4; u++)
          pins16(pk(vq[u], jt + (cc * 4 + u) * 4 + q), tv);
      }
    }
  }

  int p = b * NTOT + row0 + r;
#pragma unroll
  for (int t = 0; t < KSUB; t++)
    cval[(size_t)(q * KSUB + t) * (NBATCH * NTOT) + p] = tv[t];
}

// ---------------- KNN stage 1 (C=64/128): dot-form + packed top-16 ----------
// 128x128 tile, 8x8/thread, BK=16 staging, 3 blocks/CU. Selection reads the
// verified 128x68 Dt bounce with quad max-prefilter.
template <int C>
__global__ __launch_bounds__(256, 3) void knn_g(const float* __restrict__ feat,
                                                const float* __restrict__ sqh,
                                                unsigned* __restrict__ cval) {
  constexpr int P = 140;
  constexpr int BK = 16;
  __shared__ float As[BK * P];
  __shared__ float Bs[BK * P];
  __shared__ float Dt[128 * 68];
  __shared__ float sqB[128];

  int tid = threadIdx.x;
  int js = blockIdx.x & (JSPLIT - 1);
  int it = (blockIdx.x >> 3) & 31;
  int b = blockIdx.x >> 8;
  int i0 = it * 128;
  const float* fb = feat + (size_t)b * NTOT * C;

  int tx = tid & 15, ty = tid >> 4;
  int aoff = (ty * 8) + (((ty * 8) >> 5) << 2);
  int boff = (tx * 8) + (((tx * 8) >> 5) << 2);
  int selr = tid >> 1;
  int sels = tid & 1;

  unsigned tv[KSUB];
#pragma unroll
  for (int t = 0; t < KSUB; t++) tv[t] = 0u;

  for (int jt = 0; jt < NTOT / (128 * JSPLIT); jt++) {
    int j0 = js * (NTOT / JSPLIT) + jt * 128;
    if (tid < 128) sqB[tid] = sqh[b * NTOT + j0 + tid];

    float acc[8][8];
#pragma unroll
    for (int ii = 0; ii < 8; ii++)
#pragma unroll
      for (int jj = 0; jj < 8; jj++) acc[ii][jj] = 0.f;

    for (int kc = 0; kc < C; kc += BK) {
      __syncthreads();
#pragma unroll
      for (int l = 0; l < 2; l++) {
        int e = tid + 256 * l;
        int rr = e >> 2, c4 = e & 3;
        int sc = rr + ((rr >> 5) << 2);
        float4 va = *(const float4*)&fb[(size_t)(i0 + rr) * C + kc + c4 * 4];
        As[(c4 * 4 + 0) * P + sc] = va.x;
        As[(c4 * 4 + 1) * P + sc] = va.y;
        As[(c4 * 4 + 2) * P + sc] = va.z;
        As[(c4 * 4 + 3) * P + sc] = va.w;
        float4 vb = *(const float4*)&fb[(size_t)(j0 + rr) * C + kc + c4 * 4];
        Bs[(c4 * 4 + 0) * P + sc] = vb.x;
        Bs[(c4 * 4 + 1) * P + sc] = vb.y;
        Bs[(c4 * 4 + 2) * P + sc] = vb.z;
        Bs[(c4 * 4 + 3) * P + sc] = vb.w;
      }
      __syncthreads();
#pragma unroll 8
      for (int k = 0; k < BK; k++) {
        float4 a0 = *(const float4*)&As[k * P + aoff];
        float4 a1 = *(const float4*)&As[k * P + aoff + 4];
        float4 b0 = *(const float4*)&Bs[k * P + boff];
        float4 b1 = *(const float4*)&Bs[k * P + boff + 4];
        float av[8] = {a0.x, a0.y, a0.z, a0.w, a1.x, a1.y, a1.z, a1.w};
        float bv[8] = {b0.x, b0.y, b0.z, b0.w, b1.x, b1.y, b1.z, b1.w};
#pragma unroll
        for (int ii = 0; ii < 8; ii++)
#pragma unroll
          for (int jj = 0; jj < 8; jj++)
            acc[ii][jj] = fmaf(av[ii], bv[jj], acc[ii][jj]);
      }
    }

    // phase A: j-tile cols 0..63 (threads tx<8)
    if (tx < 8) {
      float4 q0 = *(const float4*)&sqB[tx * 8];
      float4 q1 = *(const float4*)&sqB[tx * 8 + 4];
#pragma unroll
      for (int ii = 0; ii < 8; ii++) {
        float4 o0 = make_float4(acc[ii][0] - q0.x, acc[ii][1] - q0.y,
                                acc[ii][2] - q0.z, acc[ii][3] - q0.w);
        float4 o1 = make_float4(acc[ii][4] - q1.x, acc[ii][5] - q1.y,
                                acc[ii][6] - q1.z, acc[ii][7] - q1.w);
        *(float4*)&Dt[(ty * 8 + ii) * 68 + tx * 8] = o0;
        *(float4*)&Dt[(ty * 8 + ii) * 68 + tx * 8 + 4] = o1;
      }
    }
    __syncthreads();
#pragma unroll
    for (int t4 = 0; t4 < 8; t4++) {
      float4 v = *(const float4*)&Dt[selr * 68 + sels * 32 + t4 * 4];
      pins16_quad(v, j0 + sels * 32 + t4 * 4, tv);
    }
    __syncthreads();
    // phase B: j-tile cols 64..127 (threads tx>=8)
    if (tx >= 8) {
      float4 q0 = *(const float4*)&sqB[tx * 8];
      float4 q1 = *(const float4*)&sqB[tx * 8 + 4];
#pragma unroll
      for (int ii = 0; ii < 8; ii++) {
        float4 o0 = make_float4(acc[ii][0] - q0.x, acc[ii][1] - q0.y,
                                acc[ii][2] - q0.z, acc[ii][3] - q0.w);
        float4 o1 = make_float4(acc[ii][4] - q1.x, acc[ii][5] - q1.y,
                                acc[ii][6] - q1.z, acc[ii][7] - q1.w);
        *(float4*)&Dt[(ty * 8 + ii) * 68 + (tx - 8) * 8] = o0;
        *(float4*)&Dt[(ty * 8 + ii) * 68 + (tx - 8) * 8 + 4] = o1;
      }
    }
    __syncthreads();
#pragma unroll
    for (int t4 = 0; t4 < 8; t4++) {
      float4 v = *(const float4*)&Dt[selr * 68 + sels * 32 + t4 * 4];
      pins16_quad(v, j0 + 64 + sels * 32 + t4 * 4, tv);
    }
    __syncthreads();
  }

  int p = b * NTOT + i0 + selr;
  int sub = js * 2 + sels;  // 0..15
#pragma unroll
  for (int t = 0; t < KSUB; t++)
    cval[(size_t)(sub * KSUB + t) * (NBATCH * NTOT) + p] = tv[t];
}

// ---------------- merge + exact refine ----------------
template <int C, int NSUB>
__global__ __launch_bounds__(128) void kref_k(const float* __restrict__ feat,
                                              const unsigned* __restrict__ cval,
                                              int* __restrict__ outidx) {
  int p = blockIdx.x * 128 + threadIdx.x;
  int b = p >> 12;
  unsigned tv[KMRG];
#pragma unroll
  for (int t = 0; t < KMRG; t++) tv[t] = 0u;
#pragma unroll 1
  for (int t = 0; t < NSUB * KSUB; t += 4) {
    unsigned u0 = cval[(size_t)(t + 0) * (NBATCH * NTOT) + p];
    unsigned u1 = cval[(size_t)(t + 1) * (NBATCH * NTOT) + p];
    unsigned u2 = cval[(size_t)(t + 2) * (NBATCH * NTOT) + p];
    unsigned u3 = cval[(size_t)(t + 3) * (NBATCH * NTOT) + p];
    unsigned m4 = max(max(u0, u1), max(u2, u3));
    if (m4 > tv[0]) {
      unsigned us[4] = {u0, u1, u2, u3};
#pragma unroll
      for (int w = 0; w < 4; w++) {
        unsigned u = us[w];
        if (u > tv[0]) {
          tv[0] = u;
#pragma unroll
          for (int x = 1; x < KMRG; x++) {
            unsigned mn = min(tv[0], tv[x]);
            unsigned mx = max(tv[0], tv[x]);
            tv[0] = mn;
            tv[x] = mx;
          }
        }
      }
    }
  }

  const float* fb = feat + (size_t)b * NTOT * C;
  const float* fi = fb + (size_t)(p & (NTOT - 1)) * C;
  float ev[KNN];
  int ej[KNN];
#pragma unroll
  for (int t = 0; t < KNN; t++) { ev[t] = NEG_INF; ej[t] = 0; }
  float minv = NEG_INF;
  int minp = 0;
#pragma unroll 1
  for (int u = 0; u < KMRG; u++) {
    int j = (int)(tv[u] & 0xFFFu);
    const float* fj = fb + (size_t)j * C;
    float val;
    if (C == 3) {
      float d0 = fi[0] - fj[0];
      float d1 = fi[1] - fj[1];
      float d2 = fi[2] - fj[2];
      val = -(d0 * d0 + d1 * d1 + d2 * d2);
    } else {
      float a0 = 0.f, a1 = 0.f, a2 = 0.f, a3 = 0.f;
#pragma unroll 4
      for (int c4 = 0; c4 < C / 4; c4++) {
        float4 x = *(const float4*)&fi[c4 * 4];
        float4 y = *(const float4*)&fj[c4 * 4];
        float d0 = x.x - y.x, d1 = x.y - y.y, d2 = x.z - y.z, d3 = x.w - y.w;
        a0 = fmaf(d0, d0, a0);
        a1 = fmaf(d1, d1, a1);
        a2 = fmaf(d2, d2, a2);
        a3 = fmaf(d3, d3, a3);
      }
      val = -((a0 + a1) + (a2 + a3));
    }
    topk_insert(val, j, ev, ej, minv, minp);
  }
#pragma unroll
  for (int t = 0; t < KNN; t++) outidx[(size_t)p * KNN + t] = ej[t];
}

// ---------------- 128x128 GEMM (K>=16): Y = A * Wc^T (+bias on V half) ------
__global__ __launch_bounds__(256) void gemm128(const float* __restrict__ A,
                                               const float* __restrict__ Wc,
                                               const float* __restrict__ bias,
                                               float* __restrict__ Y, int K, int N2,
                                               int O) {
  constexpr int P = 140;
  __shared__ float As[16 * P];
  __shared__ float Bs[16 * P];
  int tid = threadIdx.x;
  int n0 = blockIdx.x * 128;
  int m0 = blockIdx.y * 128;
  int tx = tid & 15, ty = tid >> 4;
  int aoff = (ty * 8) + (((ty * 8) >> 5) << 2);
  int boff = (tx * 8) + (((tx * 8) >> 5) << 2);
  float acc[8][8];
#pragma unroll
  for (int ii = 0; ii < 8; ii++)
#pragma unroll
    for (int jj = 0; jj < 8; jj++) acc[ii][jj] = 0.f;

  for (int kc = 0; kc < K; kc += 16) {
    __syncthreads();
#pragma unroll
    for (int l = 0; l < 2; l++) {
      int e = tid + 256 * l;
      int rr = e >> 2, c4 = e & 3;
      int sc = rr + ((rr >> 5) << 2);
      float4 va = *(const float4*)&A[(size_t)(m0 + rr) * K + kc + c4 * 4];
      As[(c4 * 4 + 0) * P + sc] = va.x;
      As[(c4 * 4 + 1) * P + sc] = va.y;
      As[(c4 * 4 + 2) * P + sc] = va.z;
      As[(c4 * 4 + 3) * P + sc] = va.w;
      float4 vb = *(const float4*)&Wc[(size_t)(n0 + rr) * K + kc + c4 * 4];
      Bs[(c4 * 4 + 0) * P + sc] = vb.x;
      Bs[(c4 * 4 + 1) * P + sc] = vb.y;
      Bs[(c4 * 4 + 2) * P + sc] = vb.z;
      Bs[(c4 * 4 + 3) * P + sc] = vb.w;
    }
    __syncthreads();
#pragma unroll 8
    for (int k = 0; k < 16; k++) {
      float4 a0 = *(const float4*)&As[k * P + aoff];
      float4 a1 = *(const float4*)&As[k * P + aoff + 4];
      float4 b0 = *(const float4*)&Bs[k * P + boff];
      float4 b1 = *(const float4*)&Bs[k * P + boff + 4];
      float av[8] = {a0.x, a0.y, a0.z, a0.w, a1.x, a1.y, a1.z, a1.w};
      float bv[8] = {b0.x, b0.y, b0.z, b0.w, b1.x, b1.y, b1.z, b1.w};
#pragma unroll
      for (int ii = 0; ii < 8; ii++)
#pragma unroll
        for (int jj = 0; jj < 8; jj++)
          acc[ii][jj] = fmaf(av[ii], bv[jj], acc[ii][jj]);
    }
  }

  int col0 = n0 + tx * 8;
  float bv[8];
#pragma unroll
  for (int jj = 0; jj < 8; jj++) {
    int col = col0 + jj;
    bv[jj] = (col >= O) ? bias[col - O] : 0.f;
  }
#pragma unroll
  for (int ii = 0; ii < 8; ii++) {
    int row = m0 + ty * 8 + ii;
    float4 o0, o1;
    o0.x = acc[ii][0] + bv[0];
    o0.y = acc[ii][1] + bv[1];
    o0.z = acc[ii][2] + bv[2];
    o0.w = acc[ii][3] + bv[3];
    o1.x = acc[ii][4] + bv[4];
    o1.y = acc[ii][5] + bv[5];
    o1.z = acc[ii][6] + bv[6];
    o1.w = acc[ii][7] + bv[7];
    *(float4*)&Y[(size_t)row * N2 + col0] = o0;
    *(float4*)&Y[(size_t)row * N2 + col0 + 4] = o1;
  }
}

// ---------------- small GEMM for layer 1 (K=3) ----------------
__global__ __launch_bounds__(256) void gemm_k(const float* __restrict__ A,
                                              const float* __restrict__ Wc,
                                              const float* __restrict__ bias,
                                              float* __restrict__ Y, int K, int N2,
                                              int O) {
  __shared__ float As[8 * 68];
  __shared__ float Bs[8 * 68];
  int tid = threadIdx.x;
  int n0 = blockIdx.x * 64;
  int m0 = blockIdx.y * 64;
  int tx = tid & 15, ty = tid >> 4;
  float acc[4][4] = {};
  for (int k0 = 0; k0 < K; k0 += 8) {
    __syncthreads();
    {
      int e = tid, mm = e >> 3, kk = e & 7;
      As[kk * 68 + mm] = (k0 + kk < K) ? A[(size_t)(m0 + mm) * K + k0 + kk] : 0.f;
      int nn = mm;
      Bs[kk * 68 + nn] = (k0 + kk < K) ? Wc[(size_t)(n0 + nn) * K + k0 + kk] : 0.f;
      e = tid + 256;
      mm = e >> 3;
      kk = e & 7;
      As[kk * 68 + mm] = (k0 + kk < K) ? A[(size_t)(m0 + mm) * K + k0 + kk] : 0.f;
      nn = mm;
      Bs[kk * 68 + nn] = (k0 + kk < K) ? Wc[(size_t)(n0 + nn) * K + k0 + kk] : 0.f;
    }
    __syncthreads();
#pragma unroll
    for (int kk = 0; kk < 8; kk++) {
      float4 av = *(float4*)&As[kk * 68 + ty * 4];
      float4 bv = *(float4*)&Bs[kk * 68 + tx * 4];
      float a[4] = {av.x, av.y, av.z, av.w};
      float bb2[4] = {bv.x, bv.y, bv.z, bv.w};
#pragma unroll
      for (int ii = 0; ii < 4; ii++)
#pragma unroll
        for (int jj = 0; jj < 4; jj++) acc[ii][jj] += a[ii] * bb2[jj];
    }
  }
  int col = n0 + tx * 4;
  bool isV = (col >= O);
  float b0 = 0.f, b1 = 0.f, b2 = 0.f, b3 = 0.f;
  if (isV) {
    b0 = bias[col + 0 - O];
    b1 = bias[col + 1 - O];
    b2 = bias[col + 2 - O];
    b3 = bias[col + 3 - O];
  }
#pragma unroll
  for (int ii = 0; ii < 4; ii++) {
    int row = m0 + ty * 4 + ii;
    float4 o4;
    o4.x = acc[ii][0] + b0;
    o4.y = acc[ii][1] + b1;
    o4.z = acc[ii][2] + b2;
    o4.w = acc[ii][3] + b3;
    *(float4*)&Y[(size_t)row * N2 + col] = o4;
  }
}

// ---------------- gather + max + LeakyReLU (float4) ----------------
template <int O>
__global__ __launch_bounds__(256) void gmax_v(const float* __restrict__ Y,
                                              const int* __restrict__ idx,
                                              float* __restrict__ out) {
  constexpr int T = O / 4;
  constexpr int G = 256 / T;
  int tid = threadIdx.x;
  int p = blockIdx.x * G + tid / T;
  int o4 = (tid % T) * 4;
  int b = p >> 12;
  constexpr int N2 = 2 * O;
  const int* ip = idx + (size_t)p * KNN;
  float4 m = make_float4(NEG_INF, NEG_INF, NEG_INF, NEG_INF);
#pragma unroll
  for (int k = 0; k < KNN; k++) {
    int j = ip[k];
    float4 v = *(const float4*)&Y[((size_t)(b * NTOT + j)) * N2 + o4];
    m.x = fmaxf(m.x, v.x);
    m.y = fmaxf(m.y, v.y);
    m.z = fmaxf(m.z, v.z);
    m.w = fmaxf(m.w, v.w);
  }
  float4 c = *(const float4*)&Y[(size_t)p * N2 + O + o4];
  float4 o;
  o.x = c.x + m.x;
  o.y = c.y + m.y;
  o.z = c.z + m.z;
  o.w = c.w + m.w;
  o.x = (o.x >= 0.f) ? o.x : 0.2f * o.x;
  o.y = (o.y >= 0.f) ? o.y : 0.2f * o.y;
  o.z = (o.z >= 0.f) ? o.z : 0.2f * o.z;
  o.w = (o.w >= 0.f) ? o.w : 0.2f * o.w;
  *(float4*)&out[(size_t)p * O + o4] = o;
}

// ---------------- host side ----------------
template <int C, int O>
static void run_layer(const float* fin, void* const* w5, float* fout, float* Wc,
                      float* biasb, int* idx, float* Y, float* sqh,
                      unsigned* cval, hipStream_t stream) {
  const float* W = (const float*)w5[0];
  const float* g = (const float*)w5[1];
  const float* bb = (const float*)w5[2];
  const float* mm = (const float*)w5[3];
  const float* vv = (const float*)w5[4];
  int N2 = 2 * O;
  prep_w<<<(2 * O * C + 255) / 256, 256, 0, stream>>>(W, g, bb, mm, vv, Wc, biasb, O, C);
  if (C == 3) {
    knn3_g<<<NBATCH * (NTOT / 64), 256, 0, stream>>>(fin, cval);
    kref_k<3, 4><<<NBATCH * NTOT / 128, 128, 0, stream>>>(fin, cval, idx);
    dim3 gg(N2 / 64, NBATCH * NTOT / 64);
    gemm_k<<<gg, 256, 0, stream>>>(fin, Wc, biasb, Y, C, N2, O);
  } else {
    constexpr int CC = (C == 3) ? 64 : C;
    sqh_k<CC><<<NBATCH * NTOT / 256, 256, 0, stream>>>(fin, sqh);
    knn_g<CC><<<NBATCH * 32 * JSPLIT, 256, 0, stream>>>(fin, sqh, cval);
    kref_k<CC, JSPLIT * 2><<<NBATCH * NTOT / 128, 128, 0, stream>>>(fin, cval, idx);
    dim3 gg(N2 / 128, NBATCH * NTOT / 128);
    gemm128<<<gg, 256, 0, stream>>>(fin, Wc, biasb, Y, C, N2, O);
  }
  gmax_v<O><<<NBATCH * NTOT / (256 / (O / 4)), 256, 0, stream>>>(Y, idx, fout);
}

extern "C" void kernel_launch(void* const* d_in, const int* in_sizes, int n_in,
                              void* d_out, int out_size, void* d_ws, size_t ws_size,
                              hipStream_t stream) {
  const float* x = (const float*)d_in[0];
  char* ws = (char*)d_ws;
  float* Wc = (float*)(ws + 0);            // 262144
  float* biasb = (float*)(ws + 262144);    // 1024
  int* idx = (int*)(ws + 263168);          // 1310720
  float* sqh = (float*)(ws + 1573888);     // 65536
  float* Y = (float*)(ws + 1639424);       // 33554432 -> ends 35193856
  float* x1 = (float*)(ws + 35193856);     // 4194304
  float* x2 = (float*)(ws + 39388160);     // 4194304
  float* x3 = (float*)(ws + 43582464);     // 8388608

  unsigned* cval = (unsigned*)Y;           // 16*16*16384*4 = 16.8 MB, pre-gemm

  float* outf = (float*)d_out;

  run_layer<3, 64>(x, d_in + 1, x1, Wc, biasb, idx, Y, sqh, cval, stream);
  run_layer<64, 64>(x1, d_in + 6, x2, Wc, biasb, idx, Y, sqh, cval, stream);
  run_layer<64, 128>(x2, d_in + 11, x3, Wc, biasb, idx, Y, sqh, cval, stream);
  run_layer<128, 256>(x3, d_in + 16, outf, Wc, biasb, idx, Y, sqh, cval, stream);
}

// Round 10
// 1115.396 us; speedup vs baseline: 1.3834x; 1.2481x over previous
//
#include <hip/hip_runtime.h>

#define NTOT 4096
#define NBATCH 4
#define KNN 20
#define JSPLIT 8
#define KSUB 16
#define KMRG 28

constexpr float NEG_INF = -3.0e38f;

typedef __attribute__((ext_vector_type(8))) short bf16x8;
typedef __attribute__((ext_vector_type(4))) float f32x4;

__device__ __forceinline__ unsigned pk(float f, int j) {
  unsigned u = __float_as_uint(f);
  u = (u & 0x80000000u) ? ~u : (u | 0x80000000u);
  return (u & 0xFFFFF000u) | (unsigned)j;
}

__device__ __forceinline__ void pins16(unsigned u, unsigned (&tv)[KSUB]) {
  if (u > tv[0]) {
    tv[0] = u;
#pragma unroll
    for (int x = 1; x < KSUB; x++) {
      unsigned mn = min(tv[0], tv[x]);
      unsigned mx = max(tv[0], tv[x]);
      tv[0] = mn;
      tv[x] = mx;
    }
  }
}

__device__ __forceinline__ void topk_insert(float val, int j, float (&tv)[KNN],
                                            int (&tj)[KNN], float& minv, int& minp) {
  if (val > minv) {
#pragma unroll
    for (int u = 0; u < KNN; u++) {
      bool w = (minp == u);
      tv[u] = w ? val : tv[u];
      tj[u] = w ? j : tj[u];
    }
    minv = tv[0];
    minp = 0;
#pragma unroll
    for (int u = 1; u < KNN; u++)
      if (tv[u] < minv) { minv = tv[u]; minp = u; }
  }
}

// ---------------- prep: fold BN scale into weights ----------------
__global__ void prep_w(const float* __restrict__ W, const float* __restrict__ gg,
                       const float* __restrict__ bb, const float* __restrict__ mm,
                       const float* __restrict__ vv, float* __restrict__ Wc,
                       float* __restrict__ bias, int O, int C) {
  int t = blockIdx.x * 256 + threadIdx.x;
  if (t >= 2 * O * C) return;
  int o2 = t / C, c = t - o2 * C;
  int o = (o2 < O) ? o2 : o2 - O;
  float s = gg[o] * rsqrtf(vv[o] + 1e-5f);
  float w = (o2 < O) ? W[o * 2 * C + c] * s
                     : (W[o * 2 * C + C + c] - W[o * 2 * C + c]) * s;
  Wc[o2 * C + c] = w;
  if (o2 >= O && c == 0) bias[o] = bb[o] - mm[o] * s;
}

// ---------------- split-bf16 conversion: x = hi + lo ----------------
__global__ void cvt_k(const float* __restrict__ f, ushort* __restrict__ hi,
                      ushort* __restrict__ lo) {
  int p = blockIdx.x * 256 + threadIdx.x;
  float x = f[p];
  unsigned u = __float_as_uint(x);
  unsigned h = (u + 0x7FFFu + ((u >> 16) & 1u)) >> 16;
  float hf = __uint_as_float(h << 16);
  float r = x - hf;
  unsigned v = __float_as_uint(r);
  unsigned l = (v + 0x7FFFu + ((v >> 16) & 1u)) >> 16;
  hi[p] = (ushort)h;
  lo[p] = (ushort)l;
}

// ---------------- half squared norms (exact fp32) ----------------
template <int C>
__global__ void sqh_k(const float* __restrict__ f, float* __restrict__ sqh) {
  int p = blockIdx.x * 256 + threadIdx.x;
  const float* r = f + (size_t)p * C;
  float s = 0.f;
#pragma unroll
  for (int c4 = 0; c4 < C / 4; c4++) {
    float4 v = *(const float4*)&r[c4 * 4];
    s += v.x * v.x + v.y * v.y + v.z * v.z + v.w * v.w;
  }
  sqh[p] = 0.5f * s;
}

// ---------------- KNN C=3 stage 1: packed top-16, 4 sub-lists/row ----------
__global__ __launch_bounds__(256) void knn3_g(const float* __restrict__ feat,
                                              unsigned* __restrict__ cval) {
  __shared__ __align__(16) float sA[64 * 4];

  int tid = threadIdx.x;
  int rb = blockIdx.x & 63;
  int b = blockIdx.x >> 6;
  int row0 = rb * 64;
  int r = tid >> 2, q = tid & 3;
  int i = row0 + r;
  const float* fb = feat + (size_t)b * NTOT * 3;

  float c0 = fb[(size_t)i * 3 + 0];
  float c1 = fb[(size_t)i * 3 + 1];
  float c2 = fb[(size_t)i * 3 + 2];

  unsigned tv[KSUB];
#pragma unroll
  for (int t = 0; t < KSUB; t++) tv[t] = 0u;

  for (int jt = 0; jt < NTOT; jt += 64) {
    __syncthreads();
    if (tid < 64) {
      sA[tid * 4 + 0] = fb[(size_t)(jt + tid) * 3 + 0];
      sA[tid * 4 + 1] = fb[(size_t)(jt + tid) * 3 + 1];
      sA[tid * 4 + 2] = fb[(size_t)(jt + tid) * 3 + 2];
    }
    __syncthreads();

#pragma unroll
    for (int cc = 0; cc < 4; cc++) {
      float vq[4];
#pragma unroll
      for (int u = 0; u < 4; u++) {
        int jl = (cc * 4 + u) * 4 + q;
        float d0 = c0 - sA[jl * 4];
        float d1 = c1 - sA[jl * 4 + 1];
        float d2 = c2 - sA[jl * 4 + 2];
        vq[u] = -(d0 * d0 + d1 * d1 + d2 * d2);
      }
      float m4 = fmaxf(fmaxf(vq[0], vq[1]), fmaxf(vq[2], vq[3]));
      if (pk(m4, 0xFFF) > tv[0]) {
#pragma unroll
        for (int u = 0; u < 4; u++)
          pins16(pk(vq[u], jt + (cc * 4 + u) * 4 + q), tv);
      }
    }
  }

  int p = b * NTOT + row0 + r;
#pragma unroll
  for (int t = 0; t < KSUB; t++)
    cval[(size_t)(q * KSUB + t) * (NBATCH * NTOT) + p] = tv[t];
}

// ---------------- KNN stage 1 (C=64/128): split-bf16 MFMA dot ----------
// key = hi·hi + hi·lo + lo·hi - sqh[j]; rel err ~2^-18, far below the 2^-12
// packed-key truncation the KMRG=28 exact refine already absorbs.
// 128x128 tile/block; wave w = (wi,wj) owns the 64x64 quadrant (4x4 mfma
// tiles of 16x16x32). Dt bounce + selection identical to the verified R8 code.
template <int C>
__global__ __launch_bounds__(256, 2) void knn_m(const ushort* __restrict__ Xhi,
                                                const ushort* __restrict__ Xlo,
                                                const float* __restrict__ sqh,
                                                unsigned* __restrict__ cval) {
  constexpr int RS = 40;  // LDS row stride (bf16): 32 data + 8 pad (2-way free)
  __shared__ ushort Ah[128 * RS], Al[128 * RS];
  __shared__ ushort Bh[128 * RS], Bl[128 * RS];
  __shared__ float Dt[128 * 68];
  __shared__ float sqB[128];

  int tid = threadIdx.x;
  int js = blockIdx.x & (JSPLIT - 1);
  int it = (blockIdx.x >> 3) & 31;
  int b = blockIdx.x >> 8;
  int i0 = it * 128;
  const ushort* xh = Xhi + (size_t)b * NTOT * C;
  const ushort* xl = Xlo + (size_t)b * NTOT * C;

  int l = tid & 63, wid = tid >> 6;
  int wi = wid & 1, wj = wid >> 1;
  int n = l & 15, quad = l >> 4;
  int selr = tid >> 1;
  int sels = tid & 1;

  unsigned tv[KSUB];
#pragma unroll
  for (int t = 0; t < KSUB; t++) tv[t] = 0u;

  for (int jt = 0; jt < NTOT / (128 * JSPLIT); jt++) {
    int j0 = js * (NTOT / JSPLIT) + jt * 128;
    if (tid < 128) sqB[tid] = sqh[b * NTOT + j0 + tid];

    f32x4 acc[4][4];
#pragma unroll
    for (int ti = 0; ti < 4; ti++)
#pragma unroll
      for (int tj = 0; tj < 4; tj++) acc[ti][tj] = (f32x4)(0.f);

    for (int kc = 0; kc < C; kc += 32) {
      __syncthreads();
#pragma unroll
      for (int l2 = 0; l2 < 2; l2++) {
        int e = tid + 256 * l2;
        int rr = e >> 2, ko = (e & 3) * 8;  // 128 rows x 4 16B-chunks
        *(uint4*)&Ah[rr * RS + ko] = *(const uint4*)&xh[(size_t)(i0 + rr) * C + kc + ko];
        *(uint4*)&Al[rr * RS + ko] = *(const uint4*)&xl[(size_t)(i0 + rr) * C + kc + ko];
        *(uint4*)&Bh[rr * RS + ko] = *(const uint4*)&xh[(size_t)(j0 + rr) * C + kc + ko];
        *(uint4*)&Bl[rr * RS + ko] = *(const uint4*)&xl[(size_t)(j0 + rr) * C + kc + ko];
      }
      __syncthreads();

      bf16x8 ah[4], al[4];
#pragma unroll
      for (int ti = 0; ti < 4; ti++) {
        int row = wi * 64 + ti * 16 + n;
        ah[ti] = *(const bf16x8*)&Ah[row * RS + quad * 8];
        al[ti] = *(const bf16x8*)&Al[row * RS + quad * 8];
      }
#pragma unroll
      for (int tj = 0; tj < 4; tj++) {
        int row = wj * 64 + tj * 16 + n;
        bf16x8 bh = *(const bf16x8*)&Bh[row * RS + quad * 8];
        bf16x8 bl = *(const bf16x8*)&Bl[row * RS + quad * 8];
#pragma unroll
        for (int ti = 0; ti < 4; ti++) {
          acc[ti][tj] = __builtin_amdgcn_mfma_f32_16x16x32_bf16(ah[ti], bh, acc[ti][tj], 0, 0, 0);
          acc[ti][tj] = __builtin_amdgcn_mfma_f32_16x16x32_bf16(ah[ti], bl, acc[ti][tj], 0, 0, 0);
          acc[ti][tj] = __builtin_amdgcn_mfma_f32_16x16x32_bf16(al[ti], bh, acc[ti][tj], 0, 0, 0);
        }
      }
    }

    // phase A: waves wj==0 hold j-cols 0..63. D[m][n]: m=quad*4+reg (row),
    // n=lane&15 (col) [guide §3, m89/m91-verified layout].
    if (wj == 0) {
#pragma unroll
      for (int ti = 0; ti < 4; ti++)
#pragma unroll
        for (int tj = 0; tj < 4; tj++) {
          float q = sqB[tj * 16 + n];
#pragma unroll
          for (int r = 0; r < 4; r++)
            Dt[(wi * 64 + ti * 16 + quad * 4 + r) * 68 + tj * 16 + n] =
                acc[ti][tj][r] - q;
        }
    }
    __syncthreads();
#pragma unroll
    for (int t4 = 0; t4 < 8; t4++) {
      float4 v = *(const float4*)&Dt[selr * 68 + sels * 32 + t4 * 4];
      int jb = j0 + sels * 32 + t4 * 4;
      pins16(pk(v.x, jb + 0), tv);
      pins16(pk(v.y, jb + 1), tv);
      pins16(pk(v.z, jb + 2), tv);
      pins16(pk(v.w, jb + 3), tv);
    }
    __syncthreads();
    // phase B: waves wj==1 hold j-cols 64..127 (Dt col = local col)
    if (wj == 1) {
#pragma unroll
      for (int ti = 0; ti < 4; ti++)
#pragma unroll
        for (int tj = 0; tj < 4; tj++) {
          float q = sqB[64 + tj * 16 + n];
#pragma unroll
          for (int r = 0; r < 4; r++)
            Dt[(wi * 64 + ti * 16 + quad * 4 + r) * 68 + tj * 16 + n] =
                acc[ti][tj][r] - q;
        }
    }
    __syncthreads();
#pragma unroll
    for (int t4 = 0; t4 < 8; t4++) {
      float4 v = *(const float4*)&Dt[selr * 68 + sels * 32 + t4 * 4];
      int jb = j0 + 64 + sels * 32 + t4 * 4;
      pins16(pk(v.x, jb + 0), tv);
      pins16(pk(v.y, jb + 1), tv);
      pins16(pk(v.z, jb + 2), tv);
      pins16(pk(v.w, jb + 3), tv);
    }
    __syncthreads();
  }

  int p = b * NTOT + i0 + selr;
  int sub = js * 2 + sels;  // 0..15
#pragma unroll
  for (int t = 0; t < KSUB; t++)
    cval[(size_t)(sub * KSUB + t) * (NBATCH * NTOT) + p] = tv[t];
}

// ---------------- merge + exact refine (exact fp32, unchanged) ----------------
template <int C, int NSUB>
__global__ __launch_bounds__(128) void kref_k(const float* __restrict__ feat,
                                              const unsigned* __restrict__ cval,
                                              int* __restrict__ outidx) {
  int p = blockIdx.x * 128 + threadIdx.x;
  int b = p >> 12;
  unsigned tv[KMRG];
#pragma unroll
  for (int t = 0; t < KMRG; t++) tv[t] = 0u;
#pragma unroll 1
  for (int t = 0; t < NSUB * KSUB; t += 4) {
    unsigned u0 = cval[(size_t)(t + 0) * (NBATCH * NTOT) + p];
    unsigned u1 = cval[(size_t)(t + 1) * (NBATCH * NTOT) + p];
    unsigned u2 = cval[(size_t)(t + 2) * (NBATCH * NTOT) + p];
    unsigned u3 = cval[(size_t)(t + 3) * (NBATCH * NTOT) + p];
    unsigned m4 = max(max(u0, u1), max(u2, u3));
    if (m4 > tv[0]) {
      unsigned us[4] = {u0, u1, u2, u3};
#pragma unroll
      for (int w = 0; w < 4; w++) {
        unsigned u = us[w];
        if (u > tv[0]) {
          tv[0] = u;
#pragma unroll
          for (int x = 1; x < KMRG; x++) {
            unsigned mn = min(tv[0], tv[x]);
            unsigned mx = max(tv[0], tv[x]);
            tv[0] = mn;
            tv[x] = mx;
          }
        }
      }
    }
  }

  const float* fb = feat + (size_t)b * NTOT * C;
  const float* fi = fb + (size_t)(p & (NTOT - 1)) * C;
  float ev[KNN];
  int ej[KNN];
#pragma unroll
  for (int t = 0; t < KNN; t++) { ev[t] = NEG_INF; ej[t] = 0; }
  float minv = NEG_INF;
  int minp = 0;
#pragma unroll 1
  for (int u = 0; u < KMRG; u++) {
    int j = (int)(tv[u] & 0xFFFu);
    const float* fj = fb + (size_t)j * C;
    float val;
    if (C == 3) {
      float d0 = fi[0] - fj[0];
      float d1 = fi[1] - fj[1];
      float d2 = fi[2] - fj[2];
      val = -(d0 * d0 + d1 * d1 + d2 * d2);
    } else {
      float a0 = 0.f, a1 = 0.f, a2 = 0.f, a3 = 0.f;
#pragma unroll 4
      for (int c4 = 0; c4 < C / 4; c4++) {
        float4 x = *(const float4*)&fi[c4 * 4];
        float4 y = *(const float4*)&fj[c4 * 4];
        float d0 = x.x - y.x, d1 = x.y - y.y, d2 = x.z - y.z, d3 = x.w - y.w;
        a0 = fmaf(d0, d0, a0);
        a1 = fmaf(d1, d1, a1);
        a2 = fmaf(d2, d2, a2);
        a3 = fmaf(d3, d3, a3);
      }
      val = -((a0 + a1) + (a2 + a3));
    }
    topk_insert(val, j, ev, ej, minv, minp);
  }
#pragma unroll
  for (int t = 0; t < KNN; t++) outidx[(size_t)p * KNN + t] = ej[t];
}

// ---------------- 128x128 GEMM (K>=16): Y = A * Wc^T (+bias on V half) ------
__global__ __launch_bounds__(256) void gemm128(const float* __restrict__ A,
                                               const float* __restrict__ Wc,
                                               const float* __restrict__ bias,
                                               float* __restrict__ Y, int K, int N2,
                                               int O) {
  constexpr int P = 140;
  __shared__ float As[16 * P];
  __shared__ float Bs[16 * P];
  int tid = threadIdx.x;
  int n0 = blockIdx.x * 128;
  int m0 = blockIdx.y * 128;
  int tx = tid & 15, ty = tid >> 4;
  int aoff = (ty * 8) + (((ty * 8) >> 5) << 2);
  int boff = (tx * 8) + (((tx * 8) >> 5) << 2);
  float acc[8][8];
#pragma unroll
  for (int ii = 0; ii < 8; ii++)
#pragma unroll
    for (int jj = 0; jj < 8; jj++) acc[ii][jj] = 0.f;

  for (int kc = 0; kc < K; kc += 16) {
    __syncthreads();
#pragma unroll
    for (int l = 0; l < 2; l++) {
      int e = tid + 256 * l;
      int rr = e >> 2, c4 = e & 3;
      int sc = rr + ((rr >> 5) << 2);
      float4 va = *(const float4*)&A[(size_t)(m0 + rr) * K + kc + c4 * 4];
      As[(c4 * 4 + 0) * P + sc] = va.x;
      As[(c4 * 4 + 1) * P + sc] = va.y;
      As[(c4 * 4 + 2) * P + sc] = va.z;
      As[(c4 * 4 + 3) * P + sc] = va.w;
      float4 vb = *(const float4*)&Wc[(size_t)(n0 + rr) * K + kc + c4 * 4];
      Bs[(c4 * 4 + 0) * P + sc] = vb.x;
      Bs[(c4 * 4 + 1) * P + sc] = vb.y;
      Bs[(c4 * 4 + 2) * P + sc] = vb.z;
      Bs[(c4 * 4 + 3) * P + sc] = vb.w;
    }
    __syncthreads();
#pragma unroll 8
    for (int k = 0; k < 16; k++) {
      float4 a0 = *(const float4*)&As[k * P + aoff];
      float4 a1 = *(const float4*)&As[k * P + aoff + 4];
      float4 b0 = *(const float4*)&Bs[k * P + boff];
      float4 b1 = *(const float4*)&Bs[k * P + boff + 4];
      float av[8] = {a0.x, a0.y, a0.z, a0.w, a1.x, a1.y, a1.z, a1.w};
      float bv[8] = {b0.x, b0.y, b0.z, b0.w, b1.x, b1.y, b1.z, b1.w};
#pragma unroll
      for (int ii = 0; ii < 8; ii++)
#pragma unroll
        for (int jj = 0; jj < 8; jj++)
          acc[ii][jj] = fmaf(av[ii], bv[jj], acc[ii][jj]);
    }
  }

  int col0 = n0 + tx * 8;
  float bv[8];
#pragma unroll
  for (int jj = 0; jj < 8; jj++) {
    int col = col0 + jj;
    bv[jj] = (col >= O) ? bias[col - O] : 0.f;
  }
#pragma unroll
  for (int ii = 0; ii < 8; ii++) {
    int row = m0 + ty * 8 + ii;
    float4 o0, o1;
    o0.x = acc[ii][0] + bv[0];
    o0.y = acc[ii][1] + bv[1];
    o0.z = acc[ii][2] + bv[2];
    o0.w = acc[ii][3] + bv[3];
    o1.x = acc[ii][4] + bv[4];
    o1.y = acc[ii][5] + bv[5];
    o1.z = acc[ii][6] + bv[6];
    o1.w = acc[ii][7] + bv[7];
    *(float4*)&Y[(size_t)row * N2 + col0] = o0;
    *(float4*)&Y[(size_t)row * N2 + col0 + 4] = o1;
  }
}

// ---------------- small GEMM for layer 1 (K=3) ----------------
__global__ __launch_bounds__(256) void gemm_k(const float* __restrict__ A,
                                              const float* __restrict__ Wc,
                                              const float* __restrict__ bias,
                                              float* __restrict__ Y, int K, int N2,
                                              int O) {
  __shared__ float As[8 * 68];
  __shared__ float Bs[8 * 68];
  int tid = threadIdx.x;
  int n0 = blockIdx.x * 64;
  int m0 = blockIdx.y * 64;
  int tx = tid & 15, ty = tid >> 4;
  float acc[4][4] = {};
  for (int k0 = 0; k0 < K; k0 += 8) {
    __syncthreads();
    {
      int e = tid, mm = e >> 3, kk = e & 7;
      As[kk * 68 + mm] = (k0 + kk < K) ? A[(size_t)(m0 + mm) * K + k0 + kk] : 0.f;
      int nn = mm;
      Bs[kk * 68 + nn] = (k0 + kk < K) ? Wc[(size_t)(n0 + nn) * K + k0 + kk] : 0.f;
      e = tid + 256;
      mm = e >> 3;
      kk = e & 7;
      As[kk * 68 + mm] = (k0 + kk < K) ? A[(size_t)(m0 + mm) * K + k0 + kk] : 0.f;
      nn = mm;
      Bs[kk * 68 + nn] = (k0 + kk < K) ? Wc[(size_t)(n0 + nn) * K + k0 + kk] : 0.f;
    }
    __syncthreads();
#pragma unroll
    for (int kk = 0; kk < 8; kk++) {
      float4 av = *(float4*)&As[kk * 68 + ty * 4];
      float4 bv = *(float4*)&Bs[kk * 68 + tx * 4];
      float a[4] = {av.x, av.y, av.z, av.w};
      float bb2[4] = {bv.x, bv.y, bv.z, bv.w};
#pragma unroll
      for (int ii = 0; ii < 4; ii++)
#pragma unroll
        for (int jj = 0; jj < 4; jj++) acc[ii][jj] += a[ii] * bb2[jj];
    }
  }
  int col = n0 + tx * 4;
  bool isV = (col >= O);
  float b0 = 0.f, b1 = 0.f, b2 = 0.f, b3 = 0.f;
  if (isV) {
    b0 = bias[col + 0 - O];
    b1 = bias[col + 1 - O];
    b2 = bias[col + 2 - O];
    b3 = bias[col + 3 - O];
  }
#pragma unroll
  for (int ii = 0; ii < 4; ii++) {
    int row = m0 + ty * 4 + ii;
    float4 o4;
    o4.x = acc[ii][0] + b0;
    o4.y = acc[ii][1] + b1;
    o4.z = acc[ii][2] + b2;
    o4.w = acc[ii][3] + b3;
    *(float4*)&Y[(size_t)row * N2 + col] = o4;
  }
}

// ---------------- gather + max + LeakyReLU (float4) ----------------
template <int O>
__global__ __launch_bounds__(256) void gmax_v(const float* __restrict__ Y,
                                              const int* __restrict__ idx,
                                              float* __restrict__ out) {
  constexpr int T = O / 4;
  constexpr int G = 256 / T;
  int tid = threadIdx.x;
  int p = blockIdx.x * G + tid / T;
  int o4 = (tid % T) * 4;
  int b = p >> 12;
  constexpr int N2 = 2 * O;
  const int* ip = idx + (size_t)p * KNN;
  float4 m = make_float4(NEG_INF, NEG_INF, NEG_INF, NEG_INF);
#pragma unroll
  for (int k = 0; k < KNN; k++) {
    int j = ip[k];
    float4 v = *(const float4*)&Y[((size_t)(b * NTOT + j)) * N2 + o4];
    m.x = fmaxf(m.x, v.x);
    m.y = fmaxf(m.y, v.y);
    m.z = fmaxf(m.z, v.z);
    m.w = fmaxf(m.w, v.w);
  }
  float4 c = *(const float4*)&Y[(size_t)p * N2 + O + o4];
  float4 o;
  o.x = c.x + m.x;
  o.y = c.y + m.y;
  o.z = c.z + m.z;
  o.w = c.w + m.w;
  o.x = (o.x >= 0.f) ? o.x : 0.2f * o.x;
  o.y = (o.y >= 0.f) ? o.y : 0.2f * o.y;
  o.z = (o.z >= 0.f) ? o.z : 0.2f * o.z;
  o.w = (o.w >= 0.f) ? o.w : 0.2f * o.w;
  *(float4*)&out[(size_t)p * O + o4] = o;
}

// ---------------- host side ----------------
template <int C, int O>
static void run_layer(const float* fin, void* const* w5, float* fout, float* Wc,
                      float* biasb, int* idx, float* Y, float* sqh,
                      unsigned* cval, ushort* Xhi, ushort* Xlo,
                      hipStream_t stream) {
  const float* W = (const float*)w5[0];
  const float* g = (const float*)w5[1];
  const float* bb = (const float*)w5[2];
  const float* mm = (const float*)w5[3];
  const float* vv = (const float*)w5[4];
  int N2 = 2 * O;
  prep_w<<<(2 * O * C + 255) / 256, 256, 0, stream>>>(W, g, bb, mm, vv, Wc, biasb, O, C);
  if (C == 3) {
    knn3_g<<<NBATCH * (NTOT / 64), 256, 0, stream>>>(fin, cval);
    kref_k<3, 4><<<NBATCH * NTOT / 128, 128, 0, stream>>>(fin, cval, idx);
    dim3 gg(N2 / 64, NBATCH * NTOT / 64);
    gemm_k<<<gg, 256, 0, stream>>>(fin, Wc, biasb, Y, C, N2, O);
  } else {
    constexpr int CC = (C == 3) ? 64 : C;
    cvt_k<<<NBATCH * NTOT * CC / 256, 256, 0, stream>>>(fin, Xhi, Xlo);
    sqh_k<CC><<<NBATCH * NTOT / 256, 256, 0, stream>>>(fin, sqh);
    knn_m<CC><<<NBATCH * 32 * JSPLIT, 256, 0, stream>>>(Xhi, Xlo, sqh, cval);
    kref_k<CC, JSPLIT * 2><<<NBATCH * NTOT / 128, 128, 0, stream>>>(fin, cval, idx);
    dim3 gg(N2 / 128, NBATCH * NTOT / 128);
    gemm128<<<gg, 256, 0, stream>>>(fin, Wc, biasb, Y, C, N2, O);
  }
  gmax_v<O><<<NBATCH * NTOT / (256 / (O / 4)), 256, 0, stream>>>(Y, idx, fout);
}

extern "C" void kernel_launch(void* const* d_in, const int* in_sizes, int n_in,
                              void* d_out, int out_size, void* d_ws, size_t ws_size,
                              hipStream_t stream) {
  const float* x = (const float*)d_in[0];
  char* ws = (char*)d_ws;
  float* Wc = (float*)(ws + 0);            // 262144
  float* biasb = (float*)(ws + 262144);    // 1024
  int* idx = (int*)(ws + 263168);          // 1310720
  float* sqh = (float*)(ws + 1573888);     // 65536
  float* Y = (float*)(ws + 1639424);       // 33554432 -> ends 35193856
  float* x1 = (float*)(ws + 35193856);     // 4194304
  float* x2 = (float*)(ws + 39388160);     // 4194304
  float* x3 = (float*)(ws + 43582464);     // 8388608

  // aliases inside Y (all consumed before gemm writes Y):
  unsigned* cval = (unsigned*)Y;                       // 16.8 MB
  ushort* Xhi = (ushort*)((char*)Y + 16777216);        // 4.2 MB
  ushort* Xlo = (ushort*)((char*)Y + 16777216 + 4194304);  // 4.2 MB

  float* outf = (float*)d_out;

  run_layer<3, 64>(x, d_in + 1, x1, Wc, biasb, idx, Y, sqh, cval, Xhi, Xlo, stream);
  run_layer<64, 64>(x1, d_in + 6, x2, Wc, biasb, idx, Y, sqh, cval, Xhi, Xlo, stream);
  run_layer<64, 128>(x2, d_in + 11, x3, Wc, biasb, idx, Y, sqh, cval, Xhi, Xlo, stream);
  run_layer<128, 256>(x3, d_in + 16, outf, Wc, biasb, idx, Y, sqh, cval, Xhi, Xlo, stream);
}

// Round 12
// 1099.778 us; speedup vs baseline: 1.4030x; 1.0142x over previous
//
#include <hip/hip_runtime.h>

#define NTOT 4096
#define NBATCH 4
#define KNN 20
#define JSPLIT 8
#define KSUB 16
#define KMRG 28
#define CSLOT 256  // per-point candidate slot (knn_m fills all 256; knn3 fills 64)

constexpr float NEG_INF = -3.0e38f;

typedef __attribute__((ext_vector_type(8))) short bf16x8;
typedef __attribute__((ext_vector_type(4))) float f32x4;

__device__ __forceinline__ unsigned pk(float f, int j) {
  unsigned u = __float_as_uint(f);
  u = (u & 0x80000000u) ? ~u : (u | 0x80000000u);
  return (u & 0xFFFFF000u) | (unsigned)j;
}

__device__ __forceinline__ void pins16(unsigned u, unsigned (&tv)[KSUB]) {
  if (u > tv[0]) {
    tv[0] = u;
#pragma unroll
    for (int x = 1; x < KSUB; x++) {
      unsigned mn = min(tv[0], tv[x]);
      unsigned mx = max(tv[0], tv[x]);
      tv[0] = mn;
      tv[x] = mx;
    }
  }
}

// ---------------- prep: fold BN scale into weights ----------------
__global__ void prep_w(const float* __restrict__ W, const float* __restrict__ gg,
                       const float* __restrict__ bb, const float* __restrict__ mm,
                       const float* __restrict__ vv, float* __restrict__ Wc,
                       float* __restrict__ bias, int O, int C) {
  int t = blockIdx.x * 256 + threadIdx.x;
  if (t >= 2 * O * C) return;
  int o2 = t / C, c = t - o2 * C;
  int o = (o2 < O) ? o2 : o2 - O;
  float s = gg[o] * rsqrtf(vv[o] + 1e-5f);
  float w = (o2 < O) ? W[o * 2 * C + c] * s
                     : (W[o * 2 * C + C + c] - W[o * 2 * C + c]) * s;
  Wc[o2 * C + c] = w;
  if (o2 >= O && c == 0) bias[o] = bb[o] - mm[o] * s;
}

// ---------------- split-bf16 conversion: x = hi + lo ----------------
__global__ void cvt_k(const float* __restrict__ f, ushort* __restrict__ hi,
                      ushort* __restrict__ lo) {
  int p = blockIdx.x * 256 + threadIdx.x;
  float x = f[p];
  unsigned u = __float_as_uint(x);
  unsigned h = (u + 0x7FFFu + ((u >> 16) & 1u)) >> 16;
  float hf = __uint_as_float(h << 16);
  float r = x - hf;
  unsigned v = __float_as_uint(r);
  unsigned l = (v + 0x7FFFu + ((v >> 16) & 1u)) >> 16;
  hi[p] = (ushort)h;
  lo[p] = (ushort)l;
}

// ---------------- half squared norms (exact fp32) ----------------
template <int C>
__global__ void sqh_k(const float* __restrict__ f, float* __restrict__ sqh) {
  int p = blockIdx.x * 256 + threadIdx.x;
  const float* r = f + (size_t)p * C;
  float s = 0.f;
#pragma unroll
  for (int c4 = 0; c4 < C / 4; c4++) {
    float4 v = *(const float4*)&r[c4 * 4];
    s += v.x * v.x + v.y * v.y + v.z * v.z + v.w * v.w;
  }
  sqh[p] = 0.5f * s;
}

// ---------------- KNN C=3 stage 1: packed top-16, 4 sub-lists/row ----------
__global__ __launch_bounds__(256) void knn3_g(const float* __restrict__ feat,
                                              unsigned* __restrict__ cval) {
  __shared__ __align__(16) float sA[64 * 4];

  int tid = threadIdx.x;
  int rb = blockIdx.x & 63;
  int b = blockIdx.x >> 6;
  int row0 = rb * 64;
  int r = tid >> 2, q = tid & 3;
  int i = row0 + r;
  const float* fb = feat + (size_t)b * NTOT * 3;

  float c0 = fb[(size_t)i * 3 + 0];
  float c1 = fb[(size_t)i * 3 + 1];
  float c2 = fb[(size_t)i * 3 + 2];

  unsigned tv[KSUB];
#pragma unroll
  for (int t = 0; t < KSUB; t++) tv[t] = 0u;

  for (int jt = 0; jt < NTOT; jt += 64) {
    __syncthreads();
    if (tid < 64) {
      sA[tid * 4 + 0] = fb[(size_t)(jt + tid) * 3 + 0];
      sA[tid * 4 + 1] = fb[(size_t)(jt + tid) * 3 + 1];
      sA[tid * 4 + 2] = fb[(size_t)(jt + tid) * 3 + 2];
    }
    __syncthreads();

#pragma unroll
    for (int cc = 0; cc < 4; cc++) {
      float vq[4];
#pragma unroll
      for (int u = 0; u < 4; u++) {
        int jl = (cc * 4 + u) * 4 + q;
        float d0 = c0 - sA[jl * 4];
        float d1 = c1 - sA[jl * 4 + 1];
        float d2 = c2 - sA[jl * 4 + 2];
        vq[u] = -(d0 * d0 + d1 * d1 + d2 * d2);
      }
      float m4 = fmaxf(fmaxf(vq[0], vq[1]), fmaxf(vq[2], vq[3]));
      if (pk(m4, 0xFFF) > tv[0]) {
#pragma unroll
        for (int u = 0; u < 4; u++)
          pins16(pk(vq[u], jt + (cc * 4 + u) * 4 + q), tv);
      }
    }
  }

  int p = b * NTOT + row0 + r;
  unsigned* dst = cval + (size_t)p * CSLOT + q * 16;
#pragma unroll
  for (int t4 = 0; t4 < 4; t4++) {
    uint4 o;
    o.x = tv[t4 * 4 + 0];
    o.y = tv[t4 * 4 + 1];
    o.z = tv[t4 * 4 + 2];
    o.w = tv[t4 * 4 + 3];
    *(uint4*)&dst[t4 * 4] = o;
  }
}

// ---------------- KNN stage 1 (C=64/128): split-bf16 MFMA dot ----------
template <int C>
__global__ __launch_bounds__(256, 2) void knn_m(const ushort* __restrict__ Xhi,
                                                const ushort* __restrict__ Xlo,
                                                const float* __restrict__ sqh,
                                                unsigned* __restrict__ cval) {
  constexpr int RS = 40;  // LDS row stride (bf16): 32 data + 8 pad
  __shared__ ushort Ah[128 * RS], Al[128 * RS];
  __shared__ ushort Bh[128 * RS], Bl[128 * RS];
  __shared__ float Dt[128 * 68];
  __shared__ float sqB[128];

  int tid = threadIdx.x;
  int js = blockIdx.x & (JSPLIT - 1);
  int it = (blockIdx.x >> 3) & 31;
  int b = blockIdx.x >> 8;
  int i0 = it * 128;
  const ushort* xh = Xhi + (size_t)b * NTOT * C;
  const ushort* xl = Xlo + (size_t)b * NTOT * C;

  int l = tid & 63, wid = tid >> 6;
  int wi = wid & 1, wj = wid >> 1;
  int n = l & 15, quad = l >> 4;
  int selr = tid >> 1;
  int sels = tid & 1;

  unsigned tv[KSUB];
#pragma unroll
  for (int t = 0; t < KSUB; t++) tv[t] = 0u;

  for (int jt = 0; jt < NTOT / (128 * JSPLIT); jt++) {
    int j0 = js * (NTOT / JSPLIT) + jt * 128;
    if (tid < 128) sqB[tid] = sqh[b * NTOT + j0 + tid];

    f32x4 acc[4][4];
#pragma unroll
    for (int ti = 0; ti < 4; ti++)
#pragma unroll
      for (int tj = 0; tj < 4; tj++) acc[ti][tj] = (f32x4)(0.f);

    for (int kc = 0; kc < C; kc += 32) {
      __syncthreads();
#pragma unroll
      for (int l2 = 0; l2 < 2; l2++) {
        int e = tid + 256 * l2;
        int rr = e >> 2, ko = (e & 3) * 8;
        *(uint4*)&Ah[rr * RS + ko] = *(const uint4*)&xh[(size_t)(i0 + rr) * C + kc + ko];
        *(uint4*)&Al[rr * RS + ko] = *(const uint4*)&xl[(size_t)(i0 + rr) * C + kc + ko];
        *(uint4*)&Bh[rr * RS + ko] = *(const uint4*)&xh[(size_t)(j0 + rr) * C + kc + ko];
        *(uint4*)&Bl[rr * RS + ko] = *(const uint4*)&xl[(size_t)(j0 + rr) * C + kc + ko];
      }
      __syncthreads();

      bf16x8 ah[4], al[4];
#pragma unroll
      for (int ti = 0; ti < 4; ti++) {
        int row = wi * 64 + ti * 16 + n;
        ah[ti] = *(const bf16x8*)&Ah[row * RS + quad * 8];
        al[ti] = *(const bf16x8*)&Al[row * RS + quad * 8];
      }
#pragma unroll
      for (int tj = 0; tj < 4; tj++) {
        int row = wj * 64 + tj * 16 + n;
        bf16x8 bh = *(const bf16x8*)&Bh[row * RS + quad * 8];
        bf16x8 bl = *(const bf16x8*)&Bl[row * RS + quad * 8];
#pragma unroll
        for (int ti = 0; ti < 4; ti++) {
          acc[ti][tj] = __builtin_amdgcn_mfma_f32_16x16x32_bf16(ah[ti], bh, acc[ti][tj], 0, 0, 0);
          acc[ti][tj] = __builtin_amdgcn_mfma_f32_16x16x32_bf16(ah[ti], bl, acc[ti][tj], 0, 0, 0);
          acc[ti][tj] = __builtin_amdgcn_mfma_f32_16x16x32_bf16(al[ti], bh, acc[ti][tj], 0, 0, 0);
        }
      }
    }

    // phase A: waves wj==0 hold j-cols 0..63
    if (wj == 0) {
#pragma unroll
      for (int ti = 0; ti < 4; ti++)
#pragma unroll
        for (int tj = 0; tj < 4; tj++) {
          float q = sqB[tj * 16 + n];
#pragma unroll
          for (int r = 0; r < 4; r++)
            Dt[(wi * 64 + ti * 16 + quad * 4 + r) * 68 + tj * 16 + n] =
                acc[ti][tj][r] - q;
        }
    }
    __syncthreads();
#pragma unroll
    for (int t4 = 0; t4 < 8; t4++) {
      float4 v = *(const float4*)&Dt[selr * 68 + sels * 32 + t4 * 4];
      int jb = j0 + sels * 32 + t4 * 4;
      pins16(pk(v.x, jb + 0), tv);
      pins16(pk(v.y, jb + 1), tv);
      pins16(pk(v.z, jb + 2), tv);
      pins16(pk(v.w, jb + 3), tv);
    }
    __syncthreads();
    // phase B: waves wj==1 hold j-cols 64..127
    if (wj == 1) {
#pragma unroll
      for (int ti = 0; ti < 4; ti++)
#pragma unroll
        for (int tj = 0; tj < 4; tj++) {
          float q = sqB[64 + tj * 16 + n];
#pragma unroll
          for (int r = 0; r < 4; r++)
            Dt[(wi * 64 + ti * 16 + quad * 4 + r) * 68 + tj * 16 + n] =
                acc[ti][tj][r] - q;
        }
    }
    __syncthreads();
#pragma unroll
    for (int t4 = 0; t4 < 8; t4++) {
      float4 v = *(const float4*)&Dt[selr * 68 + sels * 32 + t4 * 4];
      int jb = j0 + 64 + sels * 32 + t4 * 4;
      pins16(pk(v.x, jb + 0), tv);
      pins16(pk(v.y, jb + 1), tv);
      pins16(pk(v.z, jb + 2), tv);
      pins16(pk(v.w, jb + 3), tv);
    }
    __syncthreads();
  }

  int p = b * NTOT + i0 + selr;
  int sub = js * 2 + sels;  // 0..15 -> entries sub*16 .. sub*16+15 of the 256-slot
  unsigned* dst = cval + (size_t)p * CSLOT + sub * 16;
#pragma unroll
  for (int t4 = 0; t4 < 4; t4++) {
    uint4 o;
    o.x = tv[t4 * 4 + 0];
    o.y = tv[t4 * 4 + 1];
    o.z = tv[t4 * 4 + 2];
    o.w = tv[t4 * 4 + 3];
    *(uint4*)&dst[t4 * 4] = o;
  }
}

// ---------------- wave-per-point merge + exact refine ----------------
// One 64-lane wave per point; lanes hold 4 candidates each (uint4, coalesced).
// Merge: 28 wave-max rounds over packed keys (keys unique: 12 idx bits differ
// per point). Refine: lanes cooperatively load each candidate row, butterfly-
// reduce exact fp32 direct-difference distance; candidate u lands on lane u.
// Final: 20 wave-argmax rounds on exact fp32 (tie -> smaller j).
template <int C, int NC>
__global__ __launch_bounds__(256) void kref_w(const float* __restrict__ feat,
                                              const unsigned* __restrict__ cval,
                                              int* __restrict__ outidx) {
  int tid = threadIdx.x;
  int lane = tid & 63;
  int p = blockIdx.x * 4 + (tid >> 6);
  int b = p >> 12;
  int i = p & (NTOT - 1);
  const float* fb = feat + (size_t)b * NTOT * C;

  unsigned c0 = 0, c1 = 0, c2 = 0, c3 = 0;
  if (NC == 256) {
    uint4 cc = *(const uint4*)&cval[(size_t)p * CSLOT + lane * 4];
    c0 = cc.x;
    c1 = cc.y;
    c2 = cc.z;
    c3 = cc.w;
  } else {  // NC == 64 (knn3): entries 0..63 of the slot
    c0 = cval[(size_t)p * CSLOT + lane];
  }

  int jl[KMRG];
  int myj = -1;
#pragma unroll
  for (int t = 0; t < KMRG; t++) {
    unsigned m = max(max(c0, c1), max(c2, c3));
#pragma unroll
    for (int s = 1; s < 64; s <<= 1) m = max(m, (unsigned)__shfl_xor((int)m, s));
    jl[t] = (int)(m & 0xFFFu);
    if (lane == t) myj = (int)(m & 0xFFFu);
    if (c0 == m) c0 = 0;
    if (c1 == m) c1 = 0;
    if (c2 == m) c2 = 0;
    if (c3 == m) c3 = 0;
  }

  float myval = NEG_INF;
  if (C == 3) {
    if (lane < KMRG) {
      float x0 = fb[(size_t)i * 3 + 0];
      float x1 = fb[(size_t)i * 3 + 1];
      float x2 = fb[(size_t)i * 3 + 2];
      float y0 = fb[(size_t)myj * 3 + 0];
      float y1 = fb[(size_t)myj * 3 + 1];
      float y2 = fb[(size_t)myj * 3 + 2];
      float d0 = x0 - y0, d1 = x1 - y1, d2 = x2 - y2;
      myval = -(d0 * d0 + d1 * d1 + d2 * d2);
    }
  } else {
    constexpr int CPL = (C >= 64) ? C / 64 : 1;  // floats per lane
    float fx0, fx1 = 0.f;
    if (CPL == 2) {
      float2 xv = *(const float2*)&fb[(size_t)i * C + lane * 2];
      fx0 = xv.x;
      fx1 = xv.y;
    } else {
      fx0 = fb[(size_t)i * C + lane];
    }
#pragma unroll
    for (int u = 0; u < KMRG; u++) {
      int j = jl[u];
      float d;
      if (CPL == 2) {
        float2 yv = *(const float2*)&fb[(size_t)j * C + lane * 2];
        float dx = fx0 - yv.x, dy = fx1 - yv.y;
        d = dx * dx + dy * dy;
      } else {
        float y = fb[(size_t)j * C + lane];
        float dx = fx0 - y;
        d = dx * dx;
      }
#pragma unroll
      for (int s = 1; s < 64; s <<= 1) d += __shfl_xor(d, s);
      if (lane == u) myval = -d;
    }
  }

  // final exact top-20 across lanes (lane u holds candidate u)
  int wj = 0;
#pragma unroll
  for (int t = 0; t < KNN; t++) {
    float bv = myval;
    int bx = myj;
#pragma unroll
    for (int s = 1; s < 64; s <<= 1) {
      float ov = __shfl_xor(bv, s);
      int ox = __shfl_xor(bx, s);
      if (ov > bv || (ov == bv && ox < bx)) {
        bv = ov;
        bx = ox;
      }
    }
    if (lane == t) wj = bx;
    if (myj == bx) myval = NEG_INF;
  }
  if (lane < KNN) outidx[(size_t)p * KNN + lane] = wj;
}

// ---------------- 128x128 GEMM (K>=16): Y = A * Wc^T (+bias on V half) ------
__global__ __launch_bounds__(256) void gemm128(const float* __restrict__ A,
                                               const float* __restrict__ Wc,
                                               const float* __restrict__ bias,
                                               float* __restrict__ Y, int K, int N2,
                                               int O) {
  constexpr int P = 140;
  __shared__ float As[16 * P];
  __shared__ float Bs[16 * P];
  int tid = threadIdx.x;
  int n0 = blockIdx.x * 128;
  int m0 = blockIdx.y * 128;
  int tx = tid & 15, ty = tid >> 4;
  int aoff = (ty * 8) + (((ty * 8) >> 5) << 2);
  int boff = (tx * 8) + (((tx * 8) >> 5) << 2);
  float acc[8][8];
#pragma unroll
  for (int ii = 0; ii < 8; ii++)
#pragma unroll
    for (int jj = 0; jj < 8; jj++) acc[ii][jj] = 0.f;

  for (int kc = 0; kc < K; kc += 16) {
    __syncthreads();
#pragma unroll
    for (int l = 0; l < 2; l++) {
      int e = tid + 256 * l;
      int rr = e >> 2, c4 = e & 3;
      int sc = rr + ((rr >> 5) << 2);
      float4 va = *(const float4*)&A[(size_t)(m0 + rr) * K + kc + c4 * 4];
      As[(c4 * 4 + 0) * P + sc] = va.x;
      As[(c4 * 4 + 1) * P + sc] = va.y;
      As[(c4 * 4 + 2) * P + sc] = va.z;
      As[(c4 * 4 + 3) * P + sc] = va.w;
      float4 vb = *(const float4*)&Wc[(size_t)(n0 + rr) * K + kc + c4 * 4];
      Bs[(c4 * 4 + 0) * P + sc] = vb.x;
      Bs[(c4 * 4 + 1) * P + sc] = vb.y;
      Bs[(c4 * 4 + 2) * P + sc] = vb.z;
      Bs[(c4 * 4 + 3) * P + sc] = vb.w;
    }
    __syncthreads();
#pragma unroll 8
    for (int k = 0; k < 16; k++) {
      float4 a0 = *(const float4*)&As[k * P + aoff];
      float4 a1 = *(const float4*)&As[k * P + aoff + 4];
      float4 b0 = *(const float4*)&Bs[k * P + boff];
      float4 b1 = *(const float4*)&Bs[k * P + boff + 4];
      float av[8] = {a0.x, a0.y, a0.z, a0.w, a1.x, a1.y, a1.z, a1.w};
      float bv[8] = {b0.x, b0.y, b0.z, b0.w, b1.x, b1.y, b1.z, b1.w};
#pragma unroll
      for (int ii = 0; ii < 8; ii++)
#pragma unroll
        for (int jj = 0; jj < 8; jj++)
          acc[ii][jj] = fmaf(av[ii], bv[jj], acc[ii][jj]);
    }
  }

  int col0 = n0 + tx * 8;
  float bv[8];
#pragma unroll
  for (int jj = 0; jj < 8; jj++) {
    int col = col0 + jj;
    bv[jj] = (col >= O) ? bias[col - O] : 0.f;
  }
#pragma unroll
  for (int ii = 0; ii < 8; ii++) {
    int row = m0 + ty * 8 + ii;
    float4 o0, o1;
    o0.x = acc[ii][0] + bv[0];
    o0.y = acc[ii][1] + bv[1];
    o0.z = acc[ii][2] + bv[2];
    o0.w = acc[ii][3] + bv[3];
    o1.x = acc[ii][4] + bv[4];
    o1.y = acc[ii][5] + bv[5];
    o1.z = acc[ii][6] + bv[6];
    o1.w = acc[ii][7] + bv[7];
    *(float4*)&Y[(size_t)row * N2 + col0] = o0;
    *(float4*)&Y[(size_t)row * N2 + col0 + 4] = o1;
  }
}

// ---------------- small GEMM for layer 1 (K=3) ----------------
__global__ __launch_bounds__(256) void gemm_k(const float* __restrict__ A,
                                              const float* __restrict__ Wc,
                                              const float* __restrict__ bias,
                                              float* __restrict__ Y, int K, int N2,
                                              int O) {
  __shared__ float As[8 * 68];
  __shared__ float Bs[8 * 68];
  int tid = threadIdx.x;
  int n0 = blockIdx.x * 64;
  int m0 = blockIdx.y * 64;
  int tx = tid & 15, ty = tid >> 4;
  float acc[4][4] = {};
  for (int k0 = 0; k0 < K; k0 += 8) {
    __syncthreads();
    {
      int e = tid, mm = e >> 3, kk = e & 7;
      As[kk * 68 + mm] = (k0 + kk < K) ? A[(size_t)(m0 + mm) * K + k0 + kk] : 0.f;
      int nn = mm;
      Bs[kk * 68 + nn] = (k0 + kk < K) ? Wc[(size_t)(n0 + nn) * K + k0 + kk] : 0.f;
      e = tid + 256;
      mm = e >> 3;
      kk = e & 7;
      As[kk * 68 + mm] = (k0 + kk < K) ? A[(size_t)(m0 + mm) * K + k0 + kk] : 0.f;
      nn = mm;
      Bs[kk * 68 + nn] = (k0 + kk < K) ? Wc[(size_t)(n0 + nn) * K + k0 + kk] : 0.f;
    }
    __syncthreads();
#pragma unroll
    for (int kk = 0; kk < 8; kk++) {
      float4 av = *(float4*)&As[kk * 68 + ty * 4];
      float4 bv = *(float4*)&Bs[kk * 68 + tx * 4];
      float a[4] = {av.x, av.y, av.z, av.w};
      float bb2[4] = {bv.x, bv.y, bv.z, bv.w};
#pragma unroll
      for (int ii = 0; ii < 4; ii++)
#pragma unroll
        for (int jj = 0; jj < 4; jj++) acc[ii][jj] += a[ii] * bb2[jj];
    }
  }
  int col = n0 + tx * 4;
  bool isV = (col >= O);
  float b0 = 0.f, b1 = 0.f, b2 = 0.f, b3 = 0.f;
  if (isV) {
    b0 = bias[col + 0 - O];
    b1 = bias[col + 1 - O];
    b2 = bias[col + 2 - O];
    b3 = bias[col + 3 - O];
  }
#pragma unroll
  for (int ii = 0; ii < 4; ii++) {
    int row = m0 + ty * 4 + ii;
    float4 o4;
    o4.x = acc[ii][0] + b0;
    o4.y = acc[ii][1] + b1;
    o4.z = acc[ii][2] + b2;
    o4.w = acc[ii][3] + b3;
    *(float4*)&Y[(size_t)row * N2 + col] = o4;
  }
}

// ---------------- gather + max + LeakyReLU (float4) ----------------
template <int O>
__global__ __launch_bounds__(256) void gmax_v(const float* __restrict__ Y,
                                              const int* __restrict__ idx,
                                              float* __restrict__ out) {
  constexpr int T = O / 4;
  constexpr int G = 256 / T;
  int tid = threadIdx.x;
  int p = blockIdx.x * G + tid / T;
  int o4 = (tid % T) * 4;
  int b = p >> 12;
  constexpr int N2 = 2 * O;
  const int* ip = idx + (size_t)p * KNN;
  float4 m = make_float4(NEG_INF, NEG_INF, NEG_INF, NEG_INF);
#pragma unroll
  for (int k = 0; k < KNN; k++) {
    int j = ip[k];
    float4 v = *(const float4*)&Y[((size_t)(b * NTOT + j)) * N2 + o4];
    m.x = fmaxf(m.x, v.x);
    m.y = fmaxf(m.y, v.y);
    m.z = fmaxf(m.z, v.z);
    m.w = fmaxf(m.w, v.w);
  }
  float4 c = *(const float4*)&Y[(size_t)p * N2 + O + o4];
  float4 o;
  o.x = c.x + m.x;
  o.y = c.y + m.y;
  o.z = c.z + m.z;
  o.w = c.w + m.w;
  o.x = (o.x >= 0.f) ? o.x : 0.2f * o.x;
  o.y = (o.y >= 0.f) ? o.y : 0.2f * o.y;
  o.z = (o.z >= 0.f) ? o.z : 0.2f * o.z;
  o.w = (o.w >= 0.f) ? o.w : 0.2f * o.w;
  *(float4*)&out[(size_t)p * O + o4] = o;
}

// ---------------- host side ----------------
template <int C, int O>
static void run_layer(const float* fin, void* const* w5, float* fout, float* Wc,
                      float* biasb, int* idx, float* Y, float* sqh,
                      unsigned* cval, ushort* Xhi, ushort* Xlo,
                      hipStream_t stream) {
  const float* W = (const float*)w5[0];
  const float* g = (const float*)w5[1];
  const float* bb = (const float*)w5[2];
  const float* mm = (const float*)w5[3];
  const float* vv = (const float*)w5[4];
  int N2 = 2 * O;
  prep_w<<<(2 * O * C + 255) / 256, 256, 0, stream>>>(W, g, bb, mm, vv, Wc, biasb, O, C);
  if (C == 3) {
    knn3_g<<<NBATCH * (NTOT / 64), 256, 0, stream>>>(fin, cval);
    kref_w<3, 64><<<NBATCH * NTOT / 4, 256, 0, stream>>>(fin, cval, idx);
    dim3 gg(N2 / 64, NBATCH * NTOT / 64);
    gemm_k<<<gg, 256, 0, stream>>>(fin, Wc, biasb, Y, C, N2, O);
  } else {
    constexpr int CC = (C == 3) ? 64 : C;
    cvt_k<<<NBATCH * NTOT * CC / 256, 256, 0, stream>>>(fin, Xhi, Xlo);
    sqh_k<CC><<<NBATCH * NTOT / 256, 256, 0, stream>>>(fin, sqh);
    knn_m<CC><<<NBATCH * 32 * JSPLIT, 256, 0, stream>>>(Xhi, Xlo, sqh, cval);
    kref_w<CC, 256><<<NBATCH * NTOT / 4, 256, 0, stream>>>(fin, cval, idx);
    dim3 gg(N2 / 128, NBATCH * NTOT / 128);
    gemm128<<<gg, 256, 0, stream>>>(fin, Wc, biasb, Y, C, N2, O);
  }
  gmax_v<O><<<NBATCH * NTOT / (256 / (O / 4)), 256, 0, stream>>>(Y, idx, fout);
}

extern "C" void kernel_launch(void* const* d_in, const int* in_sizes, int n_in,
                              void* d_out, int out_size, void* d_ws, size_t ws_size,
                              hipStream_t stream) {
  const float* x = (const float*)d_in[0];
  char* ws = (char*)d_ws;
  float* Wc = (float*)(ws + 0);            // 262144
  float* biasb = (float*)(ws + 262144);    // 1024
  int* idx = (int*)(ws + 263168);          // 1310720
  float* sqh = (float*)(ws + 1573888);     // 65536
  float* Y = (float*)(ws + 1639424);       // 33554432 -> ends 35193856
  float* x1 = (float*)(ws + 35193856);     // 4194304
  float* x2 = (float*)(ws + 39388160);     // 4194304
  float* x3 = (float*)(ws + 43582464);     // 8388608

  // aliases inside Y (all consumed by kref_w before gemm writes Y):
  unsigned* cval = (unsigned*)Y;                           // 16384*256*4 = 16777216
  ushort* Xhi = (ushort*)((char*)Y + 16777216);            // 4194304
  ushort* Xlo = (ushort*)((char*)Y + 16777216 + 4194304);  // 4194304

  float* outf = (float*)d_out;

  run_layer<3, 64>(x, d_in + 1, x1, Wc, biasb, idx, Y, sqh, cval, Xhi, Xlo, stream);
  run_layer<64, 64>(x1, d_in + 6, x2, Wc, biasb, idx, Y, sqh, cval, Xhi, Xlo, stream);
  run_layer<64, 128>(x2, d_in + 11, x3, Wc, biasb, idx, Y, sqh, cval, Xhi, Xlo, stream);
  run_layer<128, 256>(x3, d_in + 16, outf, Wc, biasb, idx, Y, sqh, cval, Xhi, Xlo, stream);
}

// Round 13
// 1054.409 us; speedup vs baseline: 1.4634x; 1.0430x over previous
//
#include <hip/hip_runtime.h>

#define NTOT 4096
#define NBATCH 4
#define KNN 20
#define JSPLIT 8
#define JSPLIT3 4
#define KSUB 16
#define KMRG 28
#define CSLOT 256  // per-point candidate slot (256 entries, filled by both paths)

constexpr float NEG_INF = -3.0e38f;

typedef __attribute__((ext_vector_type(8))) short bf16x8;
typedef __attribute__((ext_vector_type(4))) float f32x4;

__device__ __forceinline__ unsigned pk(float f, int j) {
  unsigned u = __float_as_uint(f);
  u = (u & 0x80000000u) ? ~u : (u | 0x80000000u);
  return (u & 0xFFFFF000u) | (unsigned)j;
}

__device__ __forceinline__ void pins16(unsigned u, unsigned (&tv)[KSUB]) {
  if (u > tv[0]) {
    tv[0] = u;
#pragma unroll
    for (int x = 1; x < KSUB; x++) {
      unsigned mn = min(tv[0], tv[x]);
      unsigned mx = max(tv[0], tv[x]);
      tv[0] = mn;
      tv[x] = mx;
    }
  }
}

// ---------------- prep: fold BN scale into weights ----------------
__global__ void prep_w(const float* __restrict__ W, const float* __restrict__ gg,
                       const float* __restrict__ bb, const float* __restrict__ mm,
                       const float* __restrict__ vv, float* __restrict__ Wc,
                       float* __restrict__ bias, int O, int C) {
  int t = blockIdx.x * 256 + threadIdx.x;
  if (t >= 2 * O * C) return;
  int o2 = t / C, c = t - o2 * C;
  int o = (o2 < O) ? o2 : o2 - O;
  float s = gg[o] * rsqrtf(vv[o] + 1e-5f);
  float w = (o2 < O) ? W[o * 2 * C + c] * s
                     : (W[o * 2 * C + C + c] - W[o * 2 * C + c]) * s;
  Wc[o2 * C + c] = w;
  if (o2 >= O && c == 0) bias[o] = bb[o] - mm[o] * s;
}

// ---------------- split-bf16 conversion: x = hi + lo ----------------
__global__ void cvt_k(const float* __restrict__ f, ushort* __restrict__ hi,
                      ushort* __restrict__ lo) {
  int p = blockIdx.x * 256 + threadIdx.x;
  float x = f[p];
  unsigned u = __float_as_uint(x);
  unsigned h = (u + 0x7FFFu + ((u >> 16) & 1u)) >> 16;
  float hf = __uint_as_float(h << 16);
  float r = x - hf;
  unsigned v = __float_as_uint(r);
  unsigned l = (v + 0x7FFFu + ((v >> 16) & 1u)) >> 16;
  hi[p] = (ushort)h;
  lo[p] = (ushort)l;
}

// ---------------- half squared norms (exact fp32) ----------------
template <int C>
__global__ void sqh_k(const float* __restrict__ f, float* __restrict__ sqh) {
  int p = blockIdx.x * 256 + threadIdx.x;
  const float* r = f + (size_t)p * C;
  float s = 0.f;
#pragma unroll
  for (int c4 = 0; c4 < C / 4; c4++) {
    float4 v = *(const float4*)&r[c4 * 4];
    s += v.x * v.x + v.y * v.y + v.z * v.z + v.w * v.w;
  }
  sqh[p] = 0.5f * s;
}

// ---------------- KNN C=3 stage 1: 4-way j-split, 16 sub-lists/row ----------
// Grid NBATCH*64*4 = 1024 blocks (4 blocks/CU). Each block: 64 rows x j-range
// of 1024. Sub-list id = js*4+q -> 16 lists x 16 = 256 = CSLOT exactly.
__global__ __launch_bounds__(256) void knn3_g(const float* __restrict__ feat,
                                              unsigned* __restrict__ cval) {
  __shared__ __align__(16) float sA[64 * 4];

  int tid = threadIdx.x;
  int js = blockIdx.x & (JSPLIT3 - 1);
  int rb = (blockIdx.x >> 2) & 63;
  int b = blockIdx.x >> 8;
  int row0 = rb * 64;
  int r = tid >> 2, q = tid & 3;
  int i = row0 + r;
  const float* fb = feat + (size_t)b * NTOT * 3;

  float c0 = fb[(size_t)i * 3 + 0];
  float c1 = fb[(size_t)i * 3 + 1];
  float c2 = fb[(size_t)i * 3 + 2];

  unsigned tv[KSUB];
#pragma unroll
  for (int t = 0; t < KSUB; t++) tv[t] = 0u;

  for (int jt = js * (NTOT / JSPLIT3); jt < (js + 1) * (NTOT / JSPLIT3); jt += 64) {
    __syncthreads();
    if (tid < 64) {
      sA[tid * 4 + 0] = fb[(size_t)(jt + tid) * 3 + 0];
      sA[tid * 4 + 1] = fb[(size_t)(jt + tid) * 3 + 1];
      sA[tid * 4 + 2] = fb[(size_t)(jt + tid) * 3 + 2];
    }
    __syncthreads();

#pragma unroll
    for (int cc = 0; cc < 4; cc++) {
      float vq[4];
#pragma unroll
      for (int u = 0; u < 4; u++) {
        int jl = (cc * 4 + u) * 4 + q;
        float d0 = c0 - sA[jl * 4];
        float d1 = c1 - sA[jl * 4 + 1];
        float d2 = c2 - sA[jl * 4 + 2];
        vq[u] = -(d0 * d0 + d1 * d1 + d2 * d2);
      }
      float m4 = fmaxf(fmaxf(vq[0], vq[1]), fmaxf(vq[2], vq[3]));
      if (pk(m4, 0xFFF) > tv[0]) {
#pragma unroll
        for (int u = 0; u < 4; u++)
          pins16(pk(vq[u], jt + (cc * 4 + u) * 4 + q), tv);
      }
    }
  }

  int p = b * NTOT + row0 + r;
  int sub = js * 4 + q;  // 0..15
  unsigned* dst = cval + (size_t)p * CSLOT + sub * 16;
#pragma unroll
  for (int t4 = 0; t4 < 4; t4++) {
    uint4 o;
    o.x = tv[t4 * 4 + 0];
    o.y = tv[t4 * 4 + 1];
    o.z = tv[t4 * 4 + 2];
    o.w = tv[t4 * 4 + 3];
    *(uint4*)&dst[t4 * 4] = o;
  }
}

// ---------------- KNN stage 1 (C=64/128): split-bf16 MFMA dot ----------
template <int C>
__global__ __launch_bounds__(256, 2) void knn_m(const ushort* __restrict__ Xhi,
                                                const ushort* __restrict__ Xlo,
                                                const float* __restrict__ sqh,
                                                unsigned* __restrict__ cval) {
  constexpr int RS = 40;  // LDS row stride (bf16): 32 data + 8 pad
  __shared__ ushort Ah[128 * RS], Al[128 * RS];
  __shared__ ushort Bh[128 * RS], Bl[128 * RS];
  __shared__ float Dt[128 * 68];
  __shared__ float sqB[128];

  int tid = threadIdx.x;
  int js = blockIdx.x & (JSPLIT - 1);
  int it = (blockIdx.x >> 3) & 31;
  int b = blockIdx.x >> 8;
  int i0 = it * 128;
  const ushort* xh = Xhi + (size_t)b * NTOT * C;
  const ushort* xl = Xlo + (size_t)b * NTOT * C;

  int l = tid & 63, wid = tid >> 6;
  int wi = wid & 1, wj = wid >> 1;
  int n = l & 15, quad = l >> 4;
  int selr = tid >> 1;
  int sels = tid & 1;

  unsigned tv[KSUB];
#pragma unroll
  for (int t = 0; t < KSUB; t++) tv[t] = 0u;

  for (int jt = 0; jt < NTOT / (128 * JSPLIT); jt++) {
    int j0 = js * (NTOT / JSPLIT) + jt * 128;
    if (tid < 128) sqB[tid] = sqh[b * NTOT + j0 + tid];

    f32x4 acc[4][4];
#pragma unroll
    for (int ti = 0; ti < 4; ti++)
#pragma unroll
      for (int tj = 0; tj < 4; tj++) acc[ti][tj] = (f32x4)(0.f);

    for (int kc = 0; kc < C; kc += 32) {
      __syncthreads();
#pragma unroll
      for (int l2 = 0; l2 < 2; l2++) {
        int e = tid + 256 * l2;
        int rr = e >> 2, ko = (e & 3) * 8;
        *(uint4*)&Ah[rr * RS + ko] = *(const uint4*)&xh[(size_t)(i0 + rr) * C + kc + ko];
        *(uint4*)&Al[rr * RS + ko] = *(const uint4*)&xl[(size_t)(i0 + rr) * C + kc + ko];
        *(uint4*)&Bh[rr * RS + ko] = *(const uint4*)&xh[(size_t)(j0 + rr) * C + kc + ko];
        *(uint4*)&Bl[rr * RS + ko] = *(const uint4*)&xl[(size_t)(j0 + rr) * C + kc + ko];
      }
      __syncthreads();

      bf16x8 ah[4], al[4];
#pragma unroll
      for (int ti = 0; ti < 4; ti++) {
        int row = wi * 64 + ti * 16 + n;
        ah[ti] = *(const bf16x8*)&Ah[row * RS + quad * 8];
        al[ti] = *(const bf16x8*)&Al[row * RS + quad * 8];
      }
#pragma unroll
      for (int tj = 0; tj < 4; tj++) {
        int row = wj * 64 + tj * 16 + n;
        bf16x8 bh = *(const bf16x8*)&Bh[row * RS + quad * 8];
        bf16x8 bl = *(const bf16x8*)&Bl[row * RS + quad * 8];
#pragma unroll
        for (int ti = 0; ti < 4; ti++) {
          acc[ti][tj] = __builtin_amdgcn_mfma_f32_16x16x32_bf16(ah[ti], bh, acc[ti][tj], 0, 0, 0);
          acc[ti][tj] = __builtin_amdgcn_mfma_f32_16x16x32_bf16(ah[ti], bl, acc[ti][tj], 0, 0, 0);
          acc[ti][tj] = __builtin_amdgcn_mfma_f32_16x16x32_bf16(al[ti], bh, acc[ti][tj], 0, 0, 0);
        }
      }
    }

    // phase A: waves wj==0 hold j-cols 0..63
    if (wj == 0) {
#pragma unroll
      for (int ti = 0; ti < 4; ti++)
#pragma unroll
        for (int tj = 0; tj < 4; tj++) {
          float q = sqB[tj * 16 + n];
#pragma unroll
          for (int r = 0; r < 4; r++)
            Dt[(wi * 64 + ti * 16 + quad * 4 + r) * 68 + tj * 16 + n] =
                acc[ti][tj][r] - q;
        }
    }
    __syncthreads();
#pragma unroll
    for (int t4 = 0; t4 < 8; t4++) {
      float4 v = *(const float4*)&Dt[selr * 68 + sels * 32 + t4 * 4];
      int jb = j0 + sels * 32 + t4 * 4;
      pins16(pk(v.x, jb + 0), tv);
      pins16(pk(v.y, jb + 1), tv);
      pins16(pk(v.z, jb + 2), tv);
      pins16(pk(v.w, jb + 3), tv);
    }
    __syncthreads();
    // phase B: waves wj==1 hold j-cols 64..127
    if (wj == 1) {
#pragma unroll
      for (int ti = 0; ti < 4; ti++)
#pragma unroll
        for (int tj = 0; tj < 4; tj++) {
          float q = sqB[64 + tj * 16 + n];
#pragma unroll
          for (int r = 0; r < 4; r++)
            Dt[(wi * 64 + ti * 16 + quad * 4 + r) * 68 + tj * 16 + n] =
                acc[ti][tj][r] - q;
        }
    }
    __syncthreads();
#pragma unroll
    for (int t4 = 0; t4 < 8; t4++) {
      float4 v = *(const float4*)&Dt[selr * 68 + sels * 32 + t4 * 4];
      int jb = j0 + 64 + sels * 32 + t4 * 4;
      pins16(pk(v.x, jb + 0), tv);
      pins16(pk(v.y, jb + 1), tv);
      pins16(pk(v.z, jb + 2), tv);
      pins16(pk(v.w, jb + 3), tv);
    }
    __syncthreads();
  }

  int p = b * NTOT + i0 + selr;
  int sub = js * 2 + sels;  // 0..15
  unsigned* dst = cval + (size_t)p * CSLOT + sub * 16;
#pragma unroll
  for (int t4 = 0; t4 < 4; t4++) {
    uint4 o;
    o.x = tv[t4 * 4 + 0];
    o.y = tv[t4 * 4 + 1];
    o.z = tv[t4 * 4 + 2];
    o.w = tv[t4 * 4 + 3];
    *(uint4*)&dst[t4 * 4] = o;
  }
}

// ---------------- wave-per-point merge + exact refine ----------------
template <int C, int NC>
__global__ __launch_bounds__(256) void kref_w(const float* __restrict__ feat,
                                              const unsigned* __restrict__ cval,
                                              int* __restrict__ outidx) {
  int tid = threadIdx.x;
  int lane = tid & 63;
  int p = blockIdx.x * 4 + (tid >> 6);
  int b = p >> 12;
  int i = p & (NTOT - 1);
  const float* fb = feat + (size_t)b * NTOT * C;

  unsigned c0 = 0, c1 = 0, c2 = 0, c3 = 0;
  if (NC == 256) {
    uint4 cc = *(const uint4*)&cval[(size_t)p * CSLOT + lane * 4];
    c0 = cc.x;
    c1 = cc.y;
    c2 = cc.z;
    c3 = cc.w;
  } else {
    c0 = cval[(size_t)p * CSLOT + lane];
  }

  int jl[KMRG];
  int myj = -1;
#pragma unroll
  for (int t = 0; t < KMRG; t++) {
    unsigned m = max(max(c0, c1), max(c2, c3));
#pragma unroll
    for (int s = 1; s < 64; s <<= 1) m = max(m, (unsigned)__shfl_xor((int)m, s));
    jl[t] = (int)(m & 0xFFFu);
    if (lane == t) myj = (int)(m & 0xFFFu);
    if (c0 == m) c0 = 0;
    if (c1 == m) c1 = 0;
    if (c2 == m) c2 = 0;
    if (c3 == m) c3 = 0;
  }

  float myval = NEG_INF;
  if (C == 3) {
    if (lane < KMRG) {
      float x0 = fb[(size_t)i * 3 + 0];
      float x1 = fb[(size_t)i * 3 + 1];
      float x2 = fb[(size_t)i * 3 + 2];
      float y0 = fb[(size_t)myj * 3 + 0];
      float y1 = fb[(size_t)myj * 3 + 1];
      float y2 = fb[(size_t)myj * 3 + 2];
      float d0 = x0 - y0, d1 = x1 - y1, d2 = x2 - y2;
      myval = -(d0 * d0 + d1 * d1 + d2 * d2);
    }
  } else {
    constexpr int CPL = (C >= 64) ? C / 64 : 1;  // floats per lane
    float fx0, fx1 = 0.f;
    if (CPL == 2) {
      float2 xv = *(const float2*)&fb[(size_t)i * C + lane * 2];
      fx0 = xv.x;
      fx1 = xv.y;
    } else {
      fx0 = fb[(size_t)i * C + lane];
    }
#pragma unroll
    for (int u = 0; u < KMRG; u++) {
      int j = jl[u];
      float d;
      if (CPL == 2) {
        float2 yv = *(const float2*)&fb[(size_t)j * C + lane * 2];
        float dx = fx0 - yv.x, dy = fx1 - yv.y;
        d = dx * dx + dy * dy;
      } else {
        float y = fb[(size_t)j * C + lane];
        float dx = fx0 - y;
        d = dx * dx;
      }
#pragma unroll
      for (int s = 1; s < 64; s <<= 1) d += __shfl_xor(d, s);
      if (lane == u) myval = -d;
    }
  }

  // final exact top-20 across lanes (lane u holds candidate u)
  int wj = 0;
#pragma unroll
  for (int t = 0; t < KNN; t++) {
    float bv = myval;
    int bx = myj;
#pragma unroll
    for (int s = 1; s < 64; s <<= 1) {
      float ov = __shfl_xor(bv, s);
      int ox = __shfl_xor(bx, s);
      if (ov > bv || (ov == bv && ox < bx)) {
        bv = ov;
        bx = ox;
      }
    }
    if (lane == t) wj = bx;
    if (myj == bx) myval = NEG_INF;
  }
  if (lane < KNN) outidx[(size_t)p * KNN + lane] = wj;
}

// ---------------- 128x128 GEMM (K>=16): Y = A * Wc^T (+bias on V half) ------
__global__ __launch_bounds__(256) void gemm128(const float* __restrict__ A,
                                               const float* __restrict__ Wc,
                                               const float* __restrict__ bias,
                                               float* __restrict__ Y, int K, int N2,
                                               int O) {
  constexpr int P = 140;
  __shared__ float As[16 * P];
  __shared__ float Bs[16 * P];
  int tid = threadIdx.x;
  int n0 = blockIdx.x * 128;
  int m0 = blockIdx.y * 128;
  int tx = tid & 15, ty = tid >> 4;
  int aoff = (ty * 8) + (((ty * 8) >> 5) << 2);
  int boff = (tx * 8) + (((tx * 8) >> 5) << 2);
  float acc[8][8];
#pragma unroll
  for (int ii = 0; ii < 8; ii++)
#pragma unroll
    for (int jj = 0; jj < 8; jj++) acc[ii][jj] = 0.f;

  for (int kc = 0; kc < K; kc += 16) {
    __syncthreads();
#pragma unroll
    for (int l = 0; l < 2; l++) {
      int e = tid + 256 * l;
      int rr = e >> 2, c4 = e & 3;
      int sc = rr + ((rr >> 5) << 2);
      float4 va = *(const float4*)&A[(size_t)(m0 + rr) * K + kc + c4 * 4];
      As[(c4 * 4 + 0) * P + sc] = va.x;
      As[(c4 * 4 + 1) * P + sc] = va.y;
      As[(c4 * 4 + 2) * P + sc] = va.z;
      As[(c4 * 4 + 3) * P + sc] = va.w;
      float4 vb = *(const float4*)&Wc[(size_t)(n0 + rr) * K + kc + c4 * 4];
      Bs[(c4 * 4 + 0) * P + sc] = vb.x;
      Bs[(c4 * 4 + 1) * P + sc] = vb.y;
      Bs[(c4 * 4 + 2) * P + sc] = vb.z;
      Bs[(c4 * 4 + 3) * P + sc] = vb.w;
    }
    __syncthreads();
#pragma unroll 8
    for (int k = 0; k < 16; k++) {
      float4 a0 = *(const float4*)&As[k * P + aoff];
      float4 a1 = *(const float4*)&As[k * P + aoff + 4];
      float4 b0 = *(const float4*)&Bs[k * P + boff];
      float4 b1 = *(const float4*)&Bs[k * P + boff + 4];
      float av[8] = {a0.x, a0.y, a0.z, a0.w, a1.x, a1.y, a1.z, a1.w};
      float bv[8] = {b0.x, b0.y, b0.z, b0.w, b1.x, b1.y, b1.z, b1.w};
#pragma unroll
      for (int ii = 0; ii < 8; ii++)
#pragma unroll
        for (int jj = 0; jj < 8; jj++)
          acc[ii][jj] = fmaf(av[ii], bv[jj], acc[ii][jj]);
    }
  }

  int col0 = n0 + tx * 8;
  float bv[8];
#pragma unroll
  for (int jj = 0; jj < 8; jj++) {
    int col = col0 + jj;
    bv[jj] = (col >= O) ? bias[col - O] : 0.f;
  }
#pragma unroll
  for (int ii = 0; ii < 8; ii++) {
    int row = m0 + ty * 8 + ii;
    float4 o0, o1;
    o0.x = acc[ii][0] + bv[0];
    o0.y = acc[ii][1] + bv[1];
    o0.z = acc[ii][2] + bv[2];
    o0.w = acc[ii][3] + bv[3];
    o1.x = acc[ii][4] + bv[4];
    o1.y = acc[ii][5] + bv[5];
    o1.z = acc[ii][6] + bv[6];
    o1.w = acc[ii][7] + bv[7];
    *(float4*)&Y[(size_t)row * N2 + col0] = o0;
    *(float4*)&Y[(size_t)row * N2 + col0 + 4] = o1;
  }
}

// ---------------- small GEMM for layer 1 (K=3) ----------------
__global__ __launch_bounds__(256) void gemm_k(const float* __restrict__ A,
                                              const float* __restrict__ Wc,
                                              const float* __restrict__ bias,
                                              float* __restrict__ Y, int K, int N2,
                                              int O) {
  __shared__ float As[8 * 68];
  __shared__ float Bs[8 * 68];
  int tid = threadIdx.x;
  int n0 = blockIdx.x * 64;
  int m0 = blockIdx.y * 64;
  int tx = tid & 15, ty = tid >> 4;
  float acc[4][4] = {};
  for (int k0 = 0; k0 < K; k0 += 8) {
    __syncthreads();
    {
      int e = tid, mm = e >> 3, kk = e & 7;
      As[kk * 68 + mm] = (k0 + kk < K) ? A[(size_t)(m0 + mm) * K + k0 + kk] : 0.f;
      int nn = mm;
      Bs[kk * 68 + nn] = (k0 + kk < K) ? Wc[(size_t)(n0 + nn) * K + k0 + kk] : 0.f;
      e = tid + 256;
      mm = e >> 3;
      kk = e & 7;
      As[kk * 68 + mm] = (k0 + kk < K) ? A[(size_t)(m0 + mm) * K + k0 + kk] : 0.f;
      nn = mm;
      Bs[kk * 68 + nn] = (k0 + kk < K) ? Wc[(size_t)(n0 + nn) * K + k0 + kk] : 0.f;
    }
    __syncthreads();
#pragma unroll
    for (int kk = 0; kk < 8; kk++) {
      float4 av = *(float4*)&As[kk * 68 + ty * 4];
      float4 bv = *(float4*)&Bs[kk * 68 + tx * 4];
      float a[4] = {av.x, av.y, av.z, av.w};
      float bb2[4] = {bv.x, bv.y, bv.z, bv.w};
#pragma unroll
      for (int ii = 0; ii < 4; ii++)
#pragma unroll
        for (int jj = 0; jj < 4; jj++) acc[ii][jj] += a[ii] * bb2[jj];
    }
  }
  int col = n0 + tx * 4;
  bool isV = (col >= O);
  float b0 = 0.f, b1 = 0.f, b2 = 0.f, b3 = 0.f;
  if (isV) {
    b0 = bias[col + 0 - O];
    b1 = bias[col + 1 - O];
    b2 = bias[col + 2 - O];
    b3 = bias[col + 3 - O];
  }
#pragma unroll
  for (int ii = 0; ii < 4; ii++) {
    int row = m0 + ty * 4 + ii;
    float4 o4;
    o4.x = acc[ii][0] + b0;
    o4.y = acc[ii][1] + b1;
    o4.z = acc[ii][2] + b2;
    o4.w = acc[ii][3] + b3;
    *(float4*)&Y[(size_t)row * N2 + col] = o4;
  }
}

// ---------------- gather + max + LeakyReLU (float4) ----------------
template <int O>
__global__ __launch_bounds__(256) void gmax_v(const float* __restrict__ Y,
                                              const int* __restrict__ idx,
                                              float* __restrict__ out) {
  constexpr int T = O / 4;
  constexpr int G = 256 / T;
  int tid = threadIdx.x;
  int p = blockIdx.x * G + tid / T;
  int o4 = (tid % T) * 4;
  int b = p >> 12;
  constexpr int N2 = 2 * O;
  const int* ip = idx + (size_t)p * KNN;
  float4 m = make_float4(NEG_INF, NEG_INF, NEG_INF, NEG_INF);
#pragma unroll
  for (int k = 0; k < KNN; k++) {
    int j = ip[k];
    float4 v = *(const float4*)&Y[((size_t)(b * NTOT + j)) * N2 + o4];
    m.x = fmaxf(m.x, v.x);
    m.y = fmaxf(m.y, v.y);
    m.z = fmaxf(m.z, v.z);
    m.w = fmaxf(m.w, v.w);
  }
  float4 c = *(const float4*)&Y[(size_t)p * N2 + O + o4];
  float4 o;
  o.x = c.x + m.x;
  o.y = c.y + m.y;
  o.z = c.z + m.z;
  o.w = c.w + m.w;
  o.x = (o.x >= 0.f) ? o.x : 0.2f * o.x;
  o.y = (o.y >= 0.f) ? o.y : 0.2f * o.y;
  o.z = (o.z >= 0.f) ? o.z : 0.2f * o.z;
  o.w = (o.w >= 0.f) ? o.w : 0.2f * o.w;
  *(float4*)&out[(size_t)p * O + o4] = o;
}

// ---------------- host side ----------------
template <int C, int O>
static void run_layer(const float* fin, void* const* w5, float* fout, float* Wc,
                      float* biasb, int* idx, float* Y, float* sqh,
                      unsigned* cval, ushort* Xhi, ushort* Xlo,
                      hipStream_t stream) {
  const float* W = (const float*)w5[0];
  const float* g = (const float*)w5[1];
  const float* bb = (const float*)w5[2];
  const float* mm = (const float*)w5[3];
  const float* vv = (const float*)w5[4];
  int N2 = 2 * O;
  prep_w<<<(2 * O * C + 255) / 256, 256, 0, stream>>>(W, g, bb, mm, vv, Wc, biasb, O, C);
  if (C == 3) {
    knn3_g<<<NBATCH * 64 * JSPLIT3, 256, 0, stream>>>(fin, cval);
    kref_w<3, 256><<<NBATCH * NTOT / 4, 256, 0, stream>>>(fin, cval, idx);
    dim3 gg(N2 / 64, NBATCH * NTOT / 64);
    gemm_k<<<gg, 256, 0, stream>>>(fin, Wc, biasb, Y, C, N2, O);
  } else {
    constexpr int CC = (C == 3) ? 64 : C;
    cvt_k<<<NBATCH * NTOT * CC / 256, 256, 0, stream>>>(fin, Xhi, Xlo);
    sqh_k<CC><<<NBATCH * NTOT / 256, 256, 0, stream>>>(fin, sqh);
    knn_m<CC><<<NBATCH * 32 * JSPLIT, 256, 0, stream>>>(Xhi, Xlo, sqh, cval);
    kref_w<CC, 256><<<NBATCH * NTOT / 4, 256, 0, stream>>>(fin, cval, idx);
    dim3 gg(N2 / 128, NBATCH * NTOT / 128);
    gemm128<<<gg, 256, 0, stream>>>(fin, Wc, biasb, Y, C, N2, O);
  }
  gmax_v<O><<<NBATCH * NTOT / (256 / (O / 4)), 256, 0, stream>>>(Y, idx, fout);
}

extern "C" void kernel_launch(void* const* d_in, const int* in_sizes, int n_in,
                              void* d_out, int out_size, void* d_ws, size_t ws_size,
                              hipStream_t stream) {
  const float* x = (const float*)d_in[0];
  char* ws = (char*)d_ws;
  float* Wc = (float*)(ws + 0);            // 262144
  float* biasb = (float*)(ws + 262144);    // 1024
  int* idx = (int*)(ws + 263168);          // 1310720
  float* sqh = (float*)(ws + 1573888);     // 65536
  float* Y = (float*)(ws + 1639424);       // 33554432 -> ends 35193856
  float* x1 = (float*)(ws + 35193856);     // 4194304
  float* x2 = (float*)(ws + 39388160);     // 4194304
  float* x3 = (float*)(ws + 43582464);     // 8388608

  // aliases inside Y (all consumed by kref_w before gemm writes Y):
  unsigned* cval = (unsigned*)Y;                           // 16384*256*4 = 16777216
  ushort* Xhi = (ushort*)((char*)Y + 16777216);            // 4194304
  ushort* Xlo = (ushort*)((char*)Y + 16777216 + 4194304);  // 4194304

  float* outf = (float*)d_out;

  run_layer<3, 64>(x, d_in + 1, x1, Wc, biasb, idx, Y, sqh, cval, Xhi, Xlo, stream);
  run_layer<64, 64>(x1, d_in + 6, x2, Wc, biasb, idx, Y, sqh, cval, Xhi, Xlo, stream);
  run_layer<64, 128>(x2, d_in + 11, x3, Wc, biasb, idx, Y, sqh, cval, Xhi, Xlo, stream);
  run_layer<128, 256>(x3, d_in + 16, outf, Wc, biasb, idx, Y, sqh, cval, Xhi, Xlo, stream);
}